// Round 2
// baseline (11254.734 us; speedup 1.0000x reference)
//
#include <hip/hip_runtime.h>

// ---------------- problem constants (fixed by the reference) ----------------
constexpr int Bz   = 4;
constexpr int Ni   = 25000;
constexpr int BNi  = Bz * Ni;      // 100000
constexpr int DIN  = 32;
constexpr int D    = 256;
constexpr int Hh   = 8;
constexpr int DH   = 32;           // head dim
constexpr int Ll   = 6;
constexpr int NQ   = 100;
constexpr int NC1  = 19;
constexpr int HIDd = 1024;

constexpr int SEGLEN = 250;
constexpr int NSEGB  = Ni / SEGLEN;               // 100 segments per batch
constexpr float SM_SCALE = 0.17677669529663687f;  // 1/sqrt(32)

// ---------------- fused input projection (+ optional h1 path) ----------------
// inst = relu(LN(x @ ip_w.T + ip_b));  h1 = relu(x @ xm_w1.T + xm_b1)
// Outputs are LOCAL (row r of output corresponds to x row row0+r).
__global__ __launch_bounds__(256) void k_input(
    const float* __restrict__ x, int row0,
    const float* __restrict__ ip_w, const float* __restrict__ ip_b,
    const float* __restrict__ ip_g, const float* __restrict__ ip_bb,
    const float* __restrict__ xw1, const float* __restrict__ xb1,
    float* __restrict__ inst, float* __restrict__ h1)
{
    constexpr int ROWS = 4;
    const int t  = threadIdx.x;            // output column 0..255
    const int r0 = blockIdx.x * ROWS;      // local row base

    __shared__ float xs[ROWS][DIN];
    for (int idx = t; idx < ROWS * DIN; idx += 256)
        xs[idx / DIN][idx % DIN] = x[(size_t)(row0 + r0 + idx / DIN) * DIN + (idx % DIN)];
    __syncthreads();

    if (h1) {
        float wx[DIN];
        #pragma unroll
        for (int k = 0; k < DIN; k += 4) {
            float4 bv = *(const float4*)(xw1 + t * DIN + k);
            wx[k] = bv.x; wx[k+1] = bv.y; wx[k+2] = bv.z; wx[k+3] = bv.w;
        }
        const float bias = xb1[t];
        #pragma unroll
        for (int r = 0; r < ROWS; r++) {
            float a2 = bias;
            #pragma unroll
            for (int k = 0; k < DIN; k++) a2 += wx[k] * xs[r][k];
            h1[(size_t)(r0 + r) * D + t] = fmaxf(a2, 0.f);
        }
    }
    if (inst) {
        float wi[DIN];
        #pragma unroll
        for (int k = 0; k < DIN; k += 4) {
            float4 av = *(const float4*)(ip_w + t * DIN + k);
            wi[k] = av.x; wi[k+1] = av.y; wi[k+2] = av.z; wi[k+3] = av.w;
        }
        const float bias = ip_b[t];
        float y1[ROWS];
        #pragma unroll
        for (int r = 0; r < ROWS; r++) {
            float a1 = bias;
            #pragma unroll
            for (int k = 0; k < DIN; k++) a1 += wi[k] * xs[r][k];
            y1[r] = a1;
        }
        float s[ROWS], qs[ROWS];
        #pragma unroll
        for (int r = 0; r < ROWS; r++) { s[r] = y1[r]; qs[r] = y1[r] * y1[r]; }
        #pragma unroll
        for (int off = 32; off >= 1; off >>= 1) {
            #pragma unroll
            for (int r = 0; r < ROWS; r++) {
                s[r]  += __shfl_xor(s[r],  off);
                qs[r] += __shfl_xor(qs[r], off);
            }
        }
        __shared__ float red[2][4][ROWS];
        const int wid = t >> 6;
        if ((t & 63) == 0) {
            #pragma unroll
            for (int r = 0; r < ROWS; r++) { red[0][wid][r] = s[r]; red[1][wid][r] = qs[r]; }
        }
        __syncthreads();
        const float gg = ip_g[t], bb2 = ip_bb[t];
        #pragma unroll
        for (int r = 0; r < ROWS; r++) {
            float S = red[0][0][r] + red[0][1][r] + red[0][2][r] + red[0][3][r];
            float Q = red[1][0][r] + red[1][1][r] + red[1][2][r] + red[1][3][r];
            float m   = S * (1.f / D);
            float var = Q * (1.f / D) - m * m;
            float ri  = rsqrtf(var + 1e-5f);
            float val = (y1[r] - m) * ri * gg + bb2;
            inst[(size_t)(r0 + r) * D + t] = fmaxf(val, 0.f);
        }
    }
}

// ---------------- row LayerNorm (rows = grid.x, D=256, block=256) ----------------
__global__ __launch_bounds__(256) void k_ln(
    const float* __restrict__ in, float* __restrict__ out,
    const float* __restrict__ g, const float* __restrict__ b)
{
    const int t = threadIdx.x;
    const int row = blockIdx.x;
    float v = in[(size_t)row * D + t];
    float s = v, q = v * v;
    #pragma unroll
    for (int off = 32; off >= 1; off >>= 1) { s += __shfl_xor(s, off); q += __shfl_xor(q, off); }
    __shared__ float red[2][4];
    const int wid = t >> 6;
    if ((t & 63) == 0) { red[0][wid] = s; red[1][wid] = q; }
    __syncthreads();
    float S = red[0][0] + red[0][1] + red[0][2] + red[0][3];
    float Q = red[1][0] + red[1][1] + red[1][2] + red[1][3];
    float m   = S * (1.f / D);
    float var = Q * (1.f / D) - m * m;
    float ri  = rsqrtf(var + 1e-5f);
    out[(size_t)row * D + t] = (v - m) * ri * g[t] + b[t];
}

// ---------------- broadcast query_embed to (B, NQ, D) ----------------
__global__ __launch_bounds__(256) void k_bcast(const float* __restrict__ qe, float* __restrict__ q)
{
    const int t = threadIdx.x;
    const int r = blockIdx.x;                  // 0..B*NQ-1
    q[(size_t)r * D + t] = qe[(size_t)(r % NQ) * D + t];
}

// ---------------- generic fp32 GEMM: C = A(MxK) @ W(NxK)^T + bias (+resid) (+relu) ----------
template<int BM, int BN, int TM, int TN>
__global__ __launch_bounds__(256) void k_gemm(
    const float* __restrict__ A, const float* __restrict__ W,
    const float* __restrict__ bias, const float* __restrict__ resid,
    float* __restrict__ C, int M, int N, int K, int relu,
    long long sA, long long sW, long long sC)
{
    constexpr int BK = 16;
    constexpr int TX = BN / TN, TY = BM / TM;
    static_assert(TX * TY == 256, "block must be 256 threads");
    __shared__ float As[BK][BM + 4];
    __shared__ float Ws[BK][BN + 4];

    A += (size_t)blockIdx.z * sA;
    W += (size_t)blockIdx.z * sW;
    C += (size_t)blockIdx.z * sC;

    const int tid = threadIdx.x;
    const int tx = tid % TX, ty = tid / TX;
    const int row0 = blockIdx.y * BM, col0 = blockIdx.x * BN;

    float acc[TM][TN];
    #pragma unroll
    for (int i = 0; i < TM; i++)
        #pragma unroll
        for (int j = 0; j < TN; j++) acc[i][j] = 0.f;

    for (int k0 = 0; k0 < K; k0 += BK) {
        __syncthreads();
        for (int idx = tid; idx < BM * (BK / 4); idx += 256) {
            int r = idx / (BK / 4), c4 = idx % (BK / 4);
            int gr = row0 + r;
            float4 v;
            if (gr < M) v = *(const float4*)(A + (size_t)gr * K + k0 + c4 * 4);
            else { v.x = v.y = v.z = v.w = 0.f; }
            As[c4*4+0][r] = v.x; As[c4*4+1][r] = v.y; As[c4*4+2][r] = v.z; As[c4*4+3][r] = v.w;
        }
        for (int idx = tid; idx < BN * (BK / 4); idx += 256) {
            int n = idx / (BK / 4), c4 = idx % (BK / 4);
            int gn = col0 + n;
            float4 v;
            if (gn < N) v = *(const float4*)(W + (size_t)gn * K + k0 + c4 * 4);
            else { v.x = v.y = v.z = v.w = 0.f; }
            Ws[c4*4+0][n] = v.x; Ws[c4*4+1][n] = v.y; Ws[c4*4+2][n] = v.z; Ws[c4*4+3][n] = v.w;
        }
        __syncthreads();
        #pragma unroll
        for (int kk = 0; kk < BK; kk++) {
            float a[TM], bb[TN];
            #pragma unroll
            for (int i = 0; i < TM; i++) a[i] = As[kk][ty * TM + i];
            #pragma unroll
            for (int j = 0; j < TN; j++) bb[j] = Ws[kk][tx * TN + j];
            #pragma unroll
            for (int i = 0; i < TM; i++)
                #pragma unroll
                for (int j = 0; j < TN; j++)
                    acc[i][j] = fmaf(a[i], bb[j], acc[i][j]);
        }
    }

    #pragma unroll
    for (int i = 0; i < TM; i++) {
        int gr = row0 + ty * TM + i;
        if (gr >= M) continue;
        #pragma unroll
        for (int j = 0; j < TN; j++) {
            int gn = col0 + tx * TN + j;
            if (gn >= N) continue;
            float v = acc[i][j];
            if (bias)  v += bias[gn];
            if (resid) v += resid[(size_t)gr * N + gn];
            if (relu)  v = fmaxf(v, 0.f);
            C[(size_t)gr * N + gn] = v;
        }
    }
}

// ---------------- cross-attention: segmented online softmax ----------------
// grid (segsPerChunk, Hh), block 128; lane q = tid (<100 active).
// kv rows are LOCAL to the current chunk: [K(256) | V(256)] per instance.
// Writes per-(h,q,seg) partials [m, l, acc[32]] into part.
__global__ __launch_bounds__(128) void k_xattn(
    const float* __restrict__ qbuf, const float* __restrict__ kv,
    float* __restrict__ part, int b, int seg0)
{
    constexpr int CH = 64;
    const int tid = threadIdx.x;
    const int segl = blockIdx.x, h = blockIdx.y;
    const int ks = segl * SEGLEN;
    const int ke = ks + SEGLEN;

    __shared__ float Ks[CH][DH], Vs[CH][DH];

    float qr[DH];
    const int q = tid;
    if (q < NQ) {
        const float* Qp = qbuf + ((size_t)(b * NQ + q)) * D + h * DH;
        #pragma unroll
        for (int d = 0; d < DH; d += 4) {
            float4 v = *(const float4*)(Qp + d);
            qr[d] = v.x * SM_SCALE; qr[d+1] = v.y * SM_SCALE;
            qr[d+2] = v.z * SM_SCALE; qr[d+3] = v.w * SM_SCALE;
        }
    } else {
        #pragma unroll
        for (int d = 0; d < DH; d++) qr[d] = 0.f;
    }

    float m = -1e30f, l = 0.f, acc[DH];
    #pragma unroll
    for (int d = 0; d < DH; d++) acc[d] = 0.f;

    for (int c0 = ks; c0 < ke; c0 += CH) {
        const int cn = min(CH, ke - c0);
        __syncthreads();
        for (int idx = tid; idx < CH * 8; idx += 128) {
            int kk = idx >> 3, f4 = idx & 7;
            if (kk < cn) {
                const float* base = kv + ((size_t)(c0 + kk)) * (2 * D) + h * DH;
                *(float4*)&Ks[kk][f4 * 4] = *(const float4*)(base + f4 * 4);
                *(float4*)&Vs[kk][f4 * 4] = *(const float4*)(base + D + f4 * 4);
            }
        }
        __syncthreads();
        for (int kk = 0; kk < cn; kk++) {
            float sc = 0.f;
            #pragma unroll
            for (int d = 0; d < DH; d++) sc += qr[d] * Ks[kk][d];
            if (sc > m) {
                float r = __expf(m - sc);
                l *= r;
                #pragma unroll
                for (int d = 0; d < DH; d++) acc[d] *= r;
                m = sc;
            }
            float p = __expf(sc - m);
            l += p;
            #pragma unroll
            for (int d = 0; d < DH; d++) acc[d] += p * Vs[kk][d];
        }
    }

    if (q < NQ) {
        float* o = part + ((size_t)(h * NQ + q) * NSEGB + (seg0 + segl)) * 34;
        o[0] = m; o[1] = l;
        #pragma unroll
        for (int d = 0; d < DH; d++) o[2 + d] = acc[d];
    }
}

// merge NSEGB partials per (h,q) of batch b -> abuf (B*NQ, D)
__global__ __launch_bounds__(64) void k_merge(const float* __restrict__ part,
                                              float* __restrict__ abuf, int b)
{
    const int t = threadIdx.x;
    if (t >= DH) return;
    const int hq = blockIdx.x;                  // 0..Hh*NQ-1
    const int h = hq / NQ, q = hq % NQ;
    const float* p = part + (size_t)hq * NSEGB * 34;
    float mmax = -1e30f;
    for (int s = 0; s < NSEGB; s++) mmax = fmaxf(mmax, p[s * 34]);
    float L = 0.f, a = 0.f;
    for (int s = 0; s < NSEGB; s++) {
        float w = __expf(p[s * 34] - mmax);
        L += w * p[s * 34 + 1];
        a += w * p[s * 34 + 2 + t];
    }
    abuf[((size_t)(b * NQ + q)) * D + h * DH + t] = a / L;
}

// ---------------- self-attention (100x100 per (b,h)) ----------------
__global__ __launch_bounds__(128) void k_sattn(const float* __restrict__ sqkv, float* __restrict__ abuf)
{
    const int tid = threadIdx.x;
    const int bh = blockIdx.x;
    const int b = bh >> 3, h = bh & 7;
    __shared__ float Ks[NQ][DH], Vs[NQ][DH];
    for (int idx = tid; idx < NQ * 8; idx += 128) {
        int kk = idx >> 3, f4 = idx & 7;
        const float* base = sqkv + ((size_t)(b * NQ + kk)) * (3 * D) + h * DH;
        *(float4*)&Ks[kk][f4 * 4] = *(const float4*)(base + D + f4 * 4);
        *(float4*)&Vs[kk][f4 * 4] = *(const float4*)(base + 2 * D + f4 * 4);
    }
    float qr[DH];
    const int q = tid;
    if (q < NQ) {
        const float* Qp = sqkv + ((size_t)(b * NQ + q)) * (3 * D) + h * DH;
        #pragma unroll
        for (int d = 0; d < DH; d += 4) {
            float4 v = *(const float4*)(Qp + d);
            qr[d] = v.x * SM_SCALE; qr[d+1] = v.y * SM_SCALE;
            qr[d+2] = v.z * SM_SCALE; qr[d+3] = v.w * SM_SCALE;
        }
    } else {
        #pragma unroll
        for (int d = 0; d < DH; d++) qr[d] = 0.f;
    }
    __syncthreads();
    float m = -1e30f, l = 0.f, acc[DH];
    #pragma unroll
    for (int d = 0; d < DH; d++) acc[d] = 0.f;
    for (int kk = 0; kk < NQ; kk++) {
        float sc = 0.f;
        #pragma unroll
        for (int d = 0; d < DH; d++) sc += qr[d] * Ks[kk][d];
        if (sc > m) {
            float r = __expf(m - sc);
            l *= r;
            #pragma unroll
            for (int d = 0; d < DH; d++) acc[d] *= r;
            m = sc;
        }
        float p = __expf(sc - m);
        l += p;
        #pragma unroll
        for (int d = 0; d < DH; d++) acc[d] += p * Vs[kk][d];
    }
    if (q < NQ) {
        float li = 1.f / l;
        float* o = abuf + ((size_t)(b * NQ + q)) * D + h * DH;
        #pragma unroll
        for (int d = 0; d < DH; d++) o[d] = acc[d] * li;
    }
}

// ---------------- host ----------------
extern "C" void kernel_launch(void* const* d_in, const int* in_sizes, int n_in,
                              void* d_out, int out_size, void* d_ws, size_t ws_size,
                              hipStream_t stream)
{
    const float* x        = (const float*)d_in[0];
    const float* ip_w     = (const float*)d_in[2];
    const float* ip_b     = (const float*)d_in[3];
    const float* ip_g     = (const float*)d_in[4];
    const float* ip_bb    = (const float*)d_in[5];
    const float* xm_w1    = (const float*)d_in[6];
    const float* xm_b1    = (const float*)d_in[7];
    const float* xm_w2    = (const float*)d_in[8];
    const float* xm_b2    = (const float*)d_in[9];
    const float* qe       = (const float*)d_in[10];
    const float* ca_wqkv  = (const float*)d_in[11];
    const float* ca_bqkv  = (const float*)d_in[12];
    const float* ca_wo    = (const float*)d_in[13];
    const float* ca_bo    = (const float*)d_in[14];
    const float* sa_wqkv  = (const float*)d_in[15];
    const float* sa_bqkv  = (const float*)d_in[16];
    const float* sa_wo    = (const float*)d_in[17];
    const float* sa_bo    = (const float*)d_in[18];
    const float* sa_ln_g  = (const float*)d_in[19];
    const float* sa_ln_b  = (const float*)d_in[20];
    const float* ffn_w1   = (const float*)d_in[21];
    const float* ffn_b1   = (const float*)d_in[22];
    const float* ffn_w2   = (const float*)d_in[23];
    const float* ffn_b2   = (const float*)d_in[24];
    const float* ffn_ln_g = (const float*)d_in[25];
    const float* ffn_ln_b = (const float*)d_in[26];
    const float* out_ln_g = (const float*)d_in[27];
    const float* out_ln_b = (const float*)d_in[28];
    const float* cls_w1   = (const float*)d_in[29];
    const float* cls_b1   = (const float*)d_in[30];
    const float* cls_w2   = (const float*)d_in[31];
    const float* cls_b2   = (const float*)d_in[32];
    float* out = (float*)d_out;

    // ---- workspace tiering (ws_size is constant across calls -> deterministic) ----
    constexpr size_t PARTF  = (size_t)Hh * NQ * NSEGB * 34;   // 2,720,000
    constexpr size_t SMALLS = 102400 + 102400 + 307200 + 409600 + 102400 + 102400; // 1,126,400
    const size_t wsFloats = ws_size / sizeof(float);
    const size_t needA = (size_t)BNi * D + (size_t)Ni * 2 * D + PARTF + SMALLS; // 42,246,400 (169 MB)
    const size_t needB = (size_t)Ni  * D + (size_t)Ni * 2 * D + PARTF + SMALLS; // 23,046,400 (92 MB)
    const size_t needC = (size_t)Ni  * D + (size_t)12500 * 2 * D + PARTF + SMALLS; // 16,646,400 (67 MB)

    int instRows, kvRows;
    if      (wsFloats >= needA) { instRows = BNi; kvRows = Ni;    }
    else if (wsFloats >= needB) { instRows = Ni;  kvRows = Ni;    }
    else if (wsFloats >= needC) { instRows = Ni;  kvRows = 12500; }
    else return;  // workspace too small: do nothing -> clean validation failure (diagnostic)

    const bool instFull = (instRows == BNi);
    float* f0   = (float*)d_ws;
    float* inst = f0;
    float* kvb  = inst + (size_t)instRows * D;
    float* part = kvb  + (size_t)kvRows * 2 * D;
    float* qbuf = part + PARTF;
    float* abuf = qbuf + 102400;
    float* sqkv = abuf + 102400;
    float* f1b  = sqkv + 307200;
    float* qA   = f1b  + 409600;
    float* qB   = qA   + 102400;

    // input projection (inst; mask path recomputed at the end)
    if (instFull)
        k_input<<<BNi / 4, 256, 0, stream>>>(x, 0, ip_w, ip_b, ip_g, ip_bb,
                                             xm_w1, xm_b1, inst, nullptr);
    k_bcast<<<Bz * NQ, 256, 0, stream>>>(qe, qA);

    float* qcur = qA;
    float* qtmp = qB;
    for (int i = 0; i < Ll; i++) {
        const float* wqkv = ca_wqkv + (size_t)i * 3 * D * D;
        const float* bqkv = ca_bqkv + (size_t)i * 3 * D;
        // Q projection (batched over all b)
        k_gemm<64,64,4,4><<<dim3(4, 7), 256, 0, stream>>>(
            qcur, wqkv, bqkv, nullptr, qbuf, Bz * NQ, D, D, 0, 0, 0, 0);
        // cross attention per batch (chunked K/V projection + segmented softmax)
        for (int b = 0; b < Bz; b++) {
            if (!instFull)
                k_input<<<Ni / 4, 256, 0, stream>>>(x, b * Ni, ip_w, ip_b, ip_g, ip_bb,
                                                    xm_w1, xm_b1, inst, nullptr);
            const float* instb = instFull ? inst + (size_t)b * Ni * D : inst;
            for (int c0 = 0; c0 < Ni; c0 += kvRows) {
                k_gemm<32,512,16,4><<<dim3(1, (kvRows + 31) / 32), 256, 0, stream>>>(
                    instb + (size_t)c0 * D, wqkv + D * D, bqkv + D, nullptr, kvb,
                    kvRows, 2 * D, D, 0, 0, 0, 0);
                k_xattn<<<dim3(kvRows / SEGLEN, Hh), 128, 0, stream>>>(
                    qbuf, kvb, part, b, c0 / SEGLEN);
            }
            k_merge<<<Hh * NQ, 64, 0, stream>>>(part, abuf, b);
        }
        // CA out-proj + pure residual
        k_gemm<64,64,4,4><<<dim3(4, 7), 256, 0, stream>>>(
            abuf, ca_wo + (size_t)i * D * D, ca_bo + (size_t)i * D, qcur, qtmp,
            Bz * NQ, D, D, 0, 0, 0, 0);
        { float* tsw = qcur; qcur = qtmp; qtmp = tsw; }
        // self-attention
        k_gemm<64,64,4,4><<<dim3(12, 7), 256, 0, stream>>>(
            qcur, sa_wqkv + (size_t)i * 3 * D * D, sa_bqkv + (size_t)i * 3 * D, nullptr, sqkv,
            Bz * NQ, 3 * D, D, 0, 0, 0, 0);
        k_sattn<<<Bz * Hh, 128, 0, stream>>>(sqkv, abuf);
        k_gemm<64,64,4,4><<<dim3(4, 7), 256, 0, stream>>>(
            abuf, sa_wo + (size_t)i * D * D, sa_bo + (size_t)i * D, qcur, qtmp,
            Bz * NQ, D, D, 0, 0, 0, 0);
        k_ln<<<Bz * NQ, 256, 0, stream>>>(qtmp, qtmp, sa_ln_g + i * D, sa_ln_b + i * D);
        { float* tsw = qcur; qcur = qtmp; qtmp = tsw; }
        // FFN
        k_gemm<64,64,4,4><<<dim3(16, 7), 256, 0, stream>>>(
            qcur, ffn_w1 + (size_t)i * HIDd * D, ffn_b1 + (size_t)i * HIDd, nullptr, f1b,
            Bz * NQ, HIDd, D, 1, 0, 0, 0);
        k_gemm<64,64,4,4><<<dim3(4, 7), 256, 0, stream>>>(
            f1b, ffn_w2 + (size_t)i * D * HIDd, ffn_b2 + (size_t)i * D, qcur, qtmp,
            Bz * NQ, D, HIDd, 0, 0, 0, 0);
        k_ln<<<Bz * NQ, 256, 0, stream>>>(qtmp, qtmp, ffn_ln_g + i * D, ffn_ln_b + i * D);
        { float* tsw = qcur; qcur = qtmp; qtmp = tsw; }
    }

    // final LN into qbuf (free now)
    float* qn = qbuf;
    k_ln<<<Bz * NQ, 256, 0, stream>>>(qcur, qn, out_ln_g, out_ln_b);
    // classification head -> d_out[0 .. 7600)
    k_gemm<64,64,4,4><<<dim3(4, 7), 256, 0, stream>>>(
        qn, cls_w1, cls_b1, nullptr, abuf, Bz * NQ, D, D, 1, 0, 0, 0);
    k_gemm<64,64,4,4><<<dim3(1, 7), 256, 0, stream>>>(
        abuf, cls_w2, cls_b2, nullptr, out, Bz * NQ, NC1, D, 0, 0, 0, 0);

    // mask path per batch: h1 -> inst region, maskf -> kv region (both dead now)
    float* h1b   = inst;   // 6.4M floats needed, region has >= 6.4M
    float* maskf = kvb;    // 6.4M floats needed, region has >= 6.4M
    for (int b = 0; b < Bz; b++) {
        k_input<<<Ni / 4, 256, 0, stream>>>(x, b * Ni, ip_w, ip_b, ip_g, ip_bb,
                                            xm_w1, xm_b1, nullptr, h1b);
        k_gemm<32,256,8,4><<<dim3(1, (Ni + 31) / 32), 256, 0, stream>>>(
            h1b, xm_w2, xm_b2, nullptr, maskf, Ni, D, D, 0, 0, 0, 0);
        // pred_masks for batch b: qn_b(100x256) @ maskf(25000x256)^T
        k_gemm<32,512,16,4><<<dim3((Ni + 511) / 512, (NQ + 31) / 32), 256, 0, stream>>>(
            qn + (size_t)b * NQ * D, maskf, nullptr, nullptr,
            out + Bz * NQ * NC1 + (size_t)b * NQ * Ni, NQ, Ni, D, 0, 0, 0, 0);
    }
}

// Round 3
// 6344.044 us; speedup vs baseline: 1.7741x; 1.7741x over previous
//
#include <hip/hip_runtime.h>

typedef unsigned short u16;

// ---------------- problem constants ----------------
constexpr int Bz   = 4;
constexpr int Ni   = 25000;
constexpr int BNi  = Bz * Ni;      // 100000
constexpr int DIN  = 32;
constexpr int D    = 256;
constexpr int Hh   = 8;
constexpr int DH   = 32;
constexpr int Ll   = 6;
constexpr int NQ   = 100;
constexpr int NC1  = 19;
constexpr int HIDd = 1024;

constexpr int SEGLEN = 100;
constexpr int NSEGB  = Ni / SEGLEN;               // 250 segments per batch
constexpr float SM_SCALE = 0.17677669529663687f;  // 1/sqrt(32)

// ---------------- bf16 helpers ----------------
__device__ __forceinline__ u16 f2b(float f) {
    union { float f; unsigned int u; } c; c.f = f;
    unsigned int u = c.u + 0x7FFFu + ((c.u >> 16) & 1u);
    return (u16)(u >> 16);
}
__device__ __forceinline__ float b2f(u16 h) {
    union { unsigned int u; float f; } c; c.u = ((unsigned int)h) << 16;
    return c.f;
}

__global__ void k_cvt(const float* __restrict__ in, u16* __restrict__ out, int n) {
    for (int i = blockIdx.x * blockDim.x + threadIdx.x; i < n; i += gridDim.x * blockDim.x)
        out[i] = f2b(in[i]);
}

// ---------------- fused input projection (bf16 outputs) ----------------
// inst = relu(LN(x @ ip_w.T + ip_b));  h1 = relu(x @ xm_w1.T + xm_b1)
__global__ __launch_bounds__(256) void k_input(
    const float* __restrict__ x, int row0,
    const float* __restrict__ ip_w, const float* __restrict__ ip_b,
    const float* __restrict__ ip_g, const float* __restrict__ ip_bb,
    const float* __restrict__ xw1, const float* __restrict__ xb1,
    u16* __restrict__ inst, u16* __restrict__ h1)
{
    constexpr int ROWS = 4;
    const int t  = threadIdx.x;
    const int r0 = blockIdx.x * ROWS;

    __shared__ float xs[ROWS][DIN];
    for (int idx = t; idx < ROWS * DIN; idx += 256)
        xs[idx / DIN][idx % DIN] = x[(size_t)(row0 + r0 + idx / DIN) * DIN + (idx % DIN)];
    __syncthreads();

    if (h1) {
        float wx[DIN];
        #pragma unroll
        for (int k = 0; k < DIN; k += 4) {
            float4 bv = *(const float4*)(xw1 + t * DIN + k);
            wx[k] = bv.x; wx[k+1] = bv.y; wx[k+2] = bv.z; wx[k+3] = bv.w;
        }
        const float bias = xb1[t];
        #pragma unroll
        for (int r = 0; r < ROWS; r++) {
            float a2 = bias;
            #pragma unroll
            for (int k = 0; k < DIN; k++) a2 += wx[k] * xs[r][k];
            h1[(size_t)(r0 + r) * D + t] = f2b(fmaxf(a2, 0.f));
        }
    }
    if (inst) {
        float wi[DIN];
        #pragma unroll
        for (int k = 0; k < DIN; k += 4) {
            float4 av = *(const float4*)(ip_w + t * DIN + k);
            wi[k] = av.x; wi[k+1] = av.y; wi[k+2] = av.z; wi[k+3] = av.w;
        }
        const float bias = ip_b[t];
        float y1[ROWS];
        #pragma unroll
        for (int r = 0; r < ROWS; r++) {
            float a1 = bias;
            #pragma unroll
            for (int k = 0; k < DIN; k++) a1 += wi[k] * xs[r][k];
            y1[r] = a1;
        }
        float s[ROWS], qs[ROWS];
        #pragma unroll
        for (int r = 0; r < ROWS; r++) { s[r] = y1[r]; qs[r] = y1[r] * y1[r]; }
        #pragma unroll
        for (int off = 32; off >= 1; off >>= 1) {
            #pragma unroll
            for (int r = 0; r < ROWS; r++) {
                s[r]  += __shfl_xor(s[r],  off);
                qs[r] += __shfl_xor(qs[r], off);
            }
        }
        __shared__ float red[2][4][ROWS];
        const int wid = t >> 6;
        if ((t & 63) == 0) {
            #pragma unroll
            for (int r = 0; r < ROWS; r++) { red[0][wid][r] = s[r]; red[1][wid][r] = qs[r]; }
        }
        __syncthreads();
        const float gg = ip_g[t], bb2 = ip_bb[t];
        #pragma unroll
        for (int r = 0; r < ROWS; r++) {
            float S = red[0][0][r] + red[0][1][r] + red[0][2][r] + red[0][3][r];
            float Q = red[1][0][r] + red[1][1][r] + red[1][2][r] + red[1][3][r];
            float m   = S * (1.f / D);
            float var = Q * (1.f / D) - m * m;
            float ri  = rsqrtf(var + 1e-5f);
            float val = (y1[r] - m) * ri * gg + bb2;
            inst[(size_t)(r0 + r) * D + t] = f2b(fmaxf(val, 0.f));
        }
    }
}

// ---------------- row LayerNorm ----------------
__global__ __launch_bounds__(256) void k_ln(
    const float* __restrict__ in, float* __restrict__ out,
    const float* __restrict__ g, const float* __restrict__ b)
{
    const int t = threadIdx.x;
    const int row = blockIdx.x;
    float v = in[(size_t)row * D + t];
    float s = v, q = v * v;
    #pragma unroll
    for (int off = 32; off >= 1; off >>= 1) { s += __shfl_xor(s, off); q += __shfl_xor(q, off); }
    __shared__ float red[2][4];
    const int wid = t >> 6;
    if ((t & 63) == 0) { red[0][wid] = s; red[1][wid] = q; }
    __syncthreads();
    float S = red[0][0] + red[0][1] + red[0][2] + red[0][3];
    float Q = red[1][0] + red[1][1] + red[1][2] + red[1][3];
    float m   = S * (1.f / D);
    float var = Q * (1.f / D) - m * m;
    float ri  = rsqrtf(var + 1e-5f);
    out[(size_t)row * D + t] = (v - m) * ri * g[t] + b[t];
}

// ---------------- broadcast query_embed ----------------
__global__ __launch_bounds__(256) void k_bcast(const float* __restrict__ qe, float* __restrict__ q)
{
    const int t = threadIdx.x;
    const int r = blockIdx.x;
    q[(size_t)r * D + t] = qe[(size_t)(r % NQ) * D + t];
}

// ---------------- fp32 tile GEMM (small ops): C = A@W^T + bias (+resid)(+relu) --------
template<int BM, int BN, int TM, int TN>
__global__ __launch_bounds__(256) void k_gemm(
    const float* __restrict__ A, const float* __restrict__ W,
    const float* __restrict__ bias, const float* __restrict__ resid,
    float* __restrict__ C, int M, int N, int K, int relu)
{
    constexpr int BK = 16;
    constexpr int TX = BN / TN, TY = BM / TM;
    static_assert(TX * TY == 256, "block must be 256 threads");
    __shared__ float As[BK][BM + 4];
    __shared__ float Ws[BK][BN + 4];

    const int tid = threadIdx.x;
    const int tx = tid % TX, ty = tid / TX;
    const int row0 = blockIdx.y * BM, col0 = blockIdx.x * BN;

    float acc[TM][TN];
    #pragma unroll
    for (int i = 0; i < TM; i++)
        #pragma unroll
        for (int j = 0; j < TN; j++) acc[i][j] = 0.f;

    for (int k0 = 0; k0 < K; k0 += BK) {
        __syncthreads();
        for (int idx = tid; idx < BM * (BK / 4); idx += 256) {
            int r = idx / (BK / 4), c4 = idx % (BK / 4);
            int gr = row0 + r;
            float4 v;
            if (gr < M) v = *(const float4*)(A + (size_t)gr * K + k0 + c4 * 4);
            else { v.x = v.y = v.z = v.w = 0.f; }
            As[c4*4+0][r] = v.x; As[c4*4+1][r] = v.y; As[c4*4+2][r] = v.z; As[c4*4+3][r] = v.w;
        }
        for (int idx = tid; idx < BN * (BK / 4); idx += 256) {
            int n = idx / (BK / 4), c4 = idx % (BK / 4);
            int gn = col0 + n;
            float4 v;
            if (gn < N) v = *(const float4*)(W + (size_t)gn * K + k0 + c4 * 4);
            else { v.x = v.y = v.z = v.w = 0.f; }
            Ws[c4*4+0][n] = v.x; Ws[c4*4+1][n] = v.y; Ws[c4*4+2][n] = v.z; Ws[c4*4+3][n] = v.w;
        }
        __syncthreads();
        #pragma unroll
        for (int kk = 0; kk < BK; kk++) {
            float a[TM], bb[TN];
            #pragma unroll
            for (int i = 0; i < TM; i++) a[i] = As[kk][ty * TM + i];
            #pragma unroll
            for (int j = 0; j < TN; j++) bb[j] = Ws[kk][tx * TN + j];
            #pragma unroll
            for (int i = 0; i < TM; i++)
                #pragma unroll
                for (int j = 0; j < TN; j++)
                    acc[i][j] = fmaf(a[i], bb[j], acc[i][j]);
        }
    }

    #pragma unroll
    for (int i = 0; i < TM; i++) {
        int gr = row0 + ty * TM + i;
        if (gr >= M) continue;
        #pragma unroll
        for (int j = 0; j < TN; j++) {
            int gn = col0 + tx * TN + j;
            if (gn >= N) continue;
            float v = acc[i][j];
            if (bias)  v += bias[gn];
            if (resid) v += resid[(size_t)gr * N + gn];
            if (relu)  v = fmaxf(v, 0.f);
            C[(size_t)gr * N + gn] = v;
        }
    }
}

// ---------------- bf16 MFMA GEMM: C = A(MxK bf16) @ W(NxK bf16)^T + bias ----------------
// 64x64 tile, 256 threads = 4 waves, each wave 32x32 via 2x2 mfma_f32_16x16x32_bf16.
// k-within-lane loaded as 8 contiguous bf16 for BOTH operands (consistent-permutation safe).
typedef __attribute__((ext_vector_type(8))) __bf16 bf8v;
typedef __attribute__((ext_vector_type(4))) float  f4v;

template<bool OUTBF>
__global__ __launch_bounds__(256) void mm_bf16(
    const u16* __restrict__ A, const u16* __restrict__ W,
    const float* __restrict__ bias, void* __restrict__ Cv,
    int M, int N, int K)
{
    __shared__ short As[64 * 40];   // 64 rows x 32 bf16, padded to 40 (bank spread)
    __shared__ short Ws[64 * 40];
    const int tid  = threadIdx.x;
    const int lane = tid & 63, w = tid >> 6;
    const int wm = w >> 1, wn = w & 1;
    const int row0 = blockIdx.y * 64, col0 = blockIdx.x * 64;
    const int lr = lane & 15, lk = (lane >> 4) * 8;

    f4v acc[2][2];
    #pragma unroll
    for (int i = 0; i < 2; i++)
        #pragma unroll
        for (int j = 0; j < 2; j++) acc[i][j] = (f4v){0.f, 0.f, 0.f, 0.f};

    const int sr = tid >> 2, sc = (tid & 3) * 8;
    const int ga = min(row0 + sr, M - 1);
    const int gw = min(col0 + sr, N - 1);
    const u16* Ap = A + (size_t)ga * K + sc;
    const u16* Wp = W + (size_t)gw * K + sc;

    for (int k0 = 0; k0 < K; k0 += 32) {
        __syncthreads();
        *(uint4*)&As[sr * 40 + sc] = *(const uint4*)(Ap + k0);
        *(uint4*)&Ws[sr * 40 + sc] = *(const uint4*)(Wp + k0);
        __syncthreads();
        bf8v a0 = *reinterpret_cast<const bf8v*>(&As[(wm * 32      + lr) * 40 + lk]);
        bf8v a1 = *reinterpret_cast<const bf8v*>(&As[(wm * 32 + 16 + lr) * 40 + lk]);
        bf8v b0 = *reinterpret_cast<const bf8v*>(&Ws[(wn * 32      + lr) * 40 + lk]);
        bf8v b1 = *reinterpret_cast<const bf8v*>(&Ws[(wn * 32 + 16 + lr) * 40 + lk]);
        acc[0][0] = __builtin_amdgcn_mfma_f32_16x16x32_bf16(a0, b0, acc[0][0], 0, 0, 0);
        acc[0][1] = __builtin_amdgcn_mfma_f32_16x16x32_bf16(a0, b1, acc[0][1], 0, 0, 0);
        acc[1][0] = __builtin_amdgcn_mfma_f32_16x16x32_bf16(a1, b0, acc[1][0], 0, 0, 0);
        acc[1][1] = __builtin_amdgcn_mfma_f32_16x16x32_bf16(a1, b1, acc[1][1], 0, 0, 0);
    }

    // C/D layout (verified): col = lane&15, row = (lane>>4)*4 + reg
    const int crl = (lane >> 4) * 4;
    const int ccl = lane & 15;
    #pragma unroll
    for (int mi = 0; mi < 2; mi++)
        #pragma unroll
        for (int ni = 0; ni < 2; ni++)
            #pragma unroll
            for (int r = 0; r < 4; r++) {
                int grow = row0 + wm * 32 + mi * 16 + crl + r;
                int gcol = col0 + wn * 32 + ni * 16 + ccl;
                if (grow < M && gcol < N) {
                    float v = acc[mi][ni][r];
                    if (bias) v += bias[gcol];
                    if (OUTBF) ((u16*)Cv)[(size_t)grow * N + gcol] = f2b(v);
                    else       ((float*)Cv)[(size_t)grow * N + gcol] = v;
                }
            }
}

// ---------------- cross-attention: segmented online softmax over bf16 KV ----------------
// grid (segsPerChunk, Hh), block 128; lane q = tid (<100 active).
__global__ __launch_bounds__(128) void k_xattn2(
    const float* __restrict__ qbuf, const u16* __restrict__ kv,
    float* __restrict__ part, int b, int seg0)
{
    const int tid = threadIdx.x;
    const int segl = blockIdx.x, h = blockIdx.y;
    const int ks = segl * SEGLEN;

    __shared__ float Ks[SEGLEN][DH], Vs[SEGLEN][DH];

    // stage this segment's head-slice of K and V (bf16 -> fp32 LDS)
    for (int idx = tid; idx < SEGLEN * 8; idx += 128) {
        int kk = idx >> 3, g = idx & 7;
        int off = (g < 4) ? (h * DH + g * 8) : (D + h * DH + (g - 4) * 8);
        uint4 u = *(const uint4*)(kv + (size_t)(ks + kk) * (2 * D) + off);
        float* dst = (g < 4) ? &Ks[kk][(g & 3) * 8] : &Vs[kk][(g & 3) * 8];
        dst[0] = b2f((u16)u.x); dst[1] = b2f((u16)(u.x >> 16));
        dst[2] = b2f((u16)u.y); dst[3] = b2f((u16)(u.y >> 16));
        dst[4] = b2f((u16)u.z); dst[5] = b2f((u16)(u.z >> 16));
        dst[6] = b2f((u16)u.w); dst[7] = b2f((u16)(u.w >> 16));
    }

    float qr[DH];
    const int q = tid;
    if (q < NQ) {
        const float* Qp = qbuf + ((size_t)(b * NQ + q)) * D + h * DH;
        #pragma unroll
        for (int d = 0; d < DH; d += 4) {
            float4 v = *(const float4*)(Qp + d);
            qr[d] = v.x * SM_SCALE; qr[d+1] = v.y * SM_SCALE;
            qr[d+2] = v.z * SM_SCALE; qr[d+3] = v.w * SM_SCALE;
        }
    } else {
        #pragma unroll
        for (int d = 0; d < DH; d++) qr[d] = 0.f;
    }
    __syncthreads();

    float m = -1e30f, l = 0.f, acc[DH];
    #pragma unroll
    for (int d = 0; d < DH; d++) acc[d] = 0.f;

    for (int kk = 0; kk < SEGLEN; kk++) {
        float sc = 0.f;
        #pragma unroll
        for (int d4 = 0; d4 < 8; d4++) {
            float4 kx = *(const float4*)&Ks[kk][d4 * 4];
            sc += qr[d4*4] * kx.x + qr[d4*4+1] * kx.y + qr[d4*4+2] * kx.z + qr[d4*4+3] * kx.w;
        }
        if (sc > m) {
            float r = __expf(m - sc);
            l *= r;
            #pragma unroll
            for (int d = 0; d < DH; d++) acc[d] *= r;
            m = sc;
        }
        float p = __expf(sc - m);
        l += p;
        #pragma unroll
        for (int d4 = 0; d4 < 8; d4++) {
            float4 vx = *(const float4*)&Vs[kk][d4 * 4];
            acc[d4*4]   += p * vx.x; acc[d4*4+1] += p * vx.y;
            acc[d4*4+2] += p * vx.z; acc[d4*4+3] += p * vx.w;
        }
    }

    if (q < NQ) {
        float* o = part + ((size_t)(h * NQ + q) * NSEGB + (seg0 + segl)) * 34;
        o[0] = m; o[1] = l;
        #pragma unroll
        for (int d = 0; d < DH; d++) o[2 + d] = acc[d];
    }
}

// merge NSEGB partials per (h,q) of batch b -> abuf
__global__ __launch_bounds__(256) void k_merge2(const float* __restrict__ part,
                                                float* __restrict__ abuf, int b)
{
    const int t = threadIdx.x;
    const int hq = blockIdx.x;
    const int h = hq / NQ, q = hq % NQ;
    const float* p = part + (size_t)hq * NSEGB * 34;

    __shared__ float sm[256];
    float mloc = -1e30f;
    for (int s = t; s < NSEGB; s += 256) mloc = fmaxf(mloc, p[s * 34]);
    sm[t] = mloc; __syncthreads();
    for (int o = 128; o >= 1; o >>= 1) { if (t < o) sm[t] = fmaxf(sm[t], sm[t + o]); __syncthreads(); }
    const float mmax = sm[0];
    __syncthreads();

    __shared__ float wsum[256];
    __shared__ float wl[NSEGB];
    float lloc = 0.f;
    for (int s = t; s < NSEGB; s += 256) {
        float wv = __expf(p[s * 34] - mmax);
        wl[s] = wv;
        lloc += wv * p[s * 34 + 1];
    }
    wsum[t] = lloc; __syncthreads();
    for (int o = 128; o >= 1; o >>= 1) { if (t < o) wsum[t] += wsum[t + o]; __syncthreads(); }
    const float L = wsum[0];

    const int d = t & 31, sg = t >> 5;
    float a = 0.f;
    for (int s = sg; s < NSEGB; s += 8) a += wl[s] * p[s * 34 + 2 + d];
    __shared__ float accs[8][32];
    accs[sg][d] = a; __syncthreads();
    if (sg == 0) {
        float r = accs[0][d] + accs[1][d] + accs[2][d] + accs[3][d]
                + accs[4][d] + accs[5][d] + accs[6][d] + accs[7][d];
        abuf[((size_t)(b * NQ + q)) * D + h * DH + d] = r / L;
    }
}

// ---------------- self-attention (100x100 per (b,h)) ----------------
__global__ __launch_bounds__(128) void k_sattn(const float* __restrict__ sqkv, float* __restrict__ abuf)
{
    const int tid = threadIdx.x;
    const int bh = blockIdx.x;
    const int b = bh >> 3, h = bh & 7;
    __shared__ float Ks[NQ][DH], Vs[NQ][DH];
    for (int idx = tid; idx < NQ * 8; idx += 128) {
        int kk = idx >> 3, f4 = idx & 7;
        const float* base = sqkv + ((size_t)(b * NQ + kk)) * (3 * D) + h * DH;
        *(float4*)&Ks[kk][f4 * 4] = *(const float4*)(base + D + f4 * 4);
        *(float4*)&Vs[kk][f4 * 4] = *(const float4*)(base + 2 * D + f4 * 4);
    }
    float qr[DH];
    const int q = tid;
    if (q < NQ) {
        const float* Qp = sqkv + ((size_t)(b * NQ + q)) * (3 * D) + h * DH;
        #pragma unroll
        for (int d = 0; d < DH; d += 4) {
            float4 v = *(const float4*)(Qp + d);
            qr[d] = v.x * SM_SCALE; qr[d+1] = v.y * SM_SCALE;
            qr[d+2] = v.z * SM_SCALE; qr[d+3] = v.w * SM_SCALE;
        }
    } else {
        #pragma unroll
        for (int d = 0; d < DH; d++) qr[d] = 0.f;
    }
    __syncthreads();
    float m = -1e30f, l = 0.f, acc[DH];
    #pragma unroll
    for (int d = 0; d < DH; d++) acc[d] = 0.f;
    for (int kk = 0; kk < NQ; kk++) {
        float sc = 0.f;
        #pragma unroll
        for (int d = 0; d < DH; d++) sc += qr[d] * Ks[kk][d];
        if (sc > m) {
            float r = __expf(m - sc);
            l *= r;
            #pragma unroll
            for (int d = 0; d < DH; d++) acc[d] *= r;
            m = sc;
        }
        float p = __expf(sc - m);
        l += p;
        #pragma unroll
        for (int d = 0; d < DH; d++) acc[d] += p * Vs[kk][d];
    }
    if (q < NQ) {
        float li = 1.f / l;
        float* o = abuf + ((size_t)(b * NQ + q)) * D + h * DH;
        #pragma unroll
        for (int d = 0; d < DH; d++) o[d] = acc[d] * li;
    }
}

// ---------------- host ----------------
extern "C" void kernel_launch(void* const* d_in, const int* in_sizes, int n_in,
                              void* d_out, int out_size, void* d_ws, size_t ws_size,
                              hipStream_t stream)
{
    const float* x        = (const float*)d_in[0];
    const float* ip_w     = (const float*)d_in[2];
    const float* ip_b     = (const float*)d_in[3];
    const float* ip_g     = (const float*)d_in[4];
    const float* ip_bb    = (const float*)d_in[5];
    const float* xm_w1    = (const float*)d_in[6];
    const float* xm_b1    = (const float*)d_in[7];
    const float* xm_w2    = (const float*)d_in[8];
    const float* xm_b2    = (const float*)d_in[9];
    const float* qe       = (const float*)d_in[10];
    const float* ca_wqkv  = (const float*)d_in[11];
    const float* ca_bqkv  = (const float*)d_in[12];
    const float* ca_wo    = (const float*)d_in[13];
    const float* ca_bo    = (const float*)d_in[14];
    const float* sa_wqkv  = (const float*)d_in[15];
    const float* sa_bqkv  = (const float*)d_in[16];
    const float* sa_wo    = (const float*)d_in[17];
    const float* sa_bo    = (const float*)d_in[18];
    const float* sa_ln_g  = (const float*)d_in[19];
    const float* sa_ln_b  = (const float*)d_in[20];
    const float* ffn_w1   = (const float*)d_in[21];
    const float* ffn_b1   = (const float*)d_in[22];
    const float* ffn_w2   = (const float*)d_in[23];
    const float* ffn_b2   = (const float*)d_in[24];
    const float* ffn_ln_g = (const float*)d_in[25];
    const float* ffn_ln_b = (const float*)d_in[26];
    const float* out_ln_g = (const float*)d_in[27];
    const float* out_ln_b = (const float*)d_in[28];
    const float* cls_w1   = (const float*)d_in[29];
    const float* cls_b1   = (const float*)d_in[30];
    const float* cls_w2   = (const float*)d_in[31];
    const float* cls_b2   = (const float*)d_in[32];
    float* out = (float*)d_out;

    // ---- workspace tiering (bytes) ----
    // smalls: part 27.2MB + fp32 smalls + bf16 weights ~ 34.5MB
    const size_t needA = 111300000ull;   // inst full bf16 (51.2M) + kv full (25.6M) + rest
    const size_t needB =  72900000ull;   // inst per-batch   (12.8M) + kv full (25.6M)
    const size_t needC =  60100000ull;   // inst per-batch + kv half (12.8M)

    int instRows, kvRows;
    if      (ws_size >= needA) { instRows = BNi; kvRows = Ni;    }
    else if (ws_size >= needB) { instRows = Ni;  kvRows = Ni;    }
    else if (ws_size >= needC) { instRows = Ni;  kvRows = 12500; }
    else return;
    const bool instFull = (instRows == BNi);

    char* wp = (char*)d_ws;
    auto alloc = [&](size_t bytes) -> char* {
        char* r = wp; wp += (bytes + 255) & ~(size_t)255; return r;
    };
    u16*   instb = (u16*)  alloc((size_t)instRows * D * 2);
    u16*   kvb   = (u16*)  alloc((size_t)kvRows * 2 * D * 2);
    float* part  = (float*)alloc((size_t)Hh * NQ * NSEGB * 34 * 4);
    float* qbuf  = (float*)alloc(409600);
    float* abuf  = (float*)alloc(409600);
    float* sqkv  = (float*)alloc(1228800);
    float* f1b   = (float*)alloc(1638400);
    float* qA    = (float*)alloc(409600);
    float* qB    = (float*)alloc(409600);
    u16*   wqkvb = (u16*)  alloc((size_t)Ll * 3 * D * D * 2);
    u16*   xw2b  = (u16*)  alloc((size_t)D * D * 2);
    u16*   qnb   = (u16*)  alloc((size_t)Bz * NQ * D * 2);

    // weight conversions (cheap, once per call)
    k_cvt<<<1024, 256, 0, stream>>>(ca_wqkv, wqkvb, Ll * 3 * D * D);
    k_cvt<<<64,   256, 0, stream>>>(xm_w2, xw2b, D * D);

    if (instFull)
        k_input<<<BNi / 4, 256, 0, stream>>>(x, 0, ip_w, ip_b, ip_g, ip_bb,
                                             xm_w1, xm_b1, instb, nullptr);
    k_bcast<<<Bz * NQ, 256, 0, stream>>>(qe, qA);

    float* qcur = qA;
    float* qtmp = qB;
    for (int i = 0; i < Ll; i++) {
        const float* wqkv = ca_wqkv + (size_t)i * 3 * D * D;
        const float* bqkv = ca_bqkv + (size_t)i * 3 * D;
        const u16*   wkvb = wqkvb + (size_t)i * 3 * D * D + (size_t)D * D;  // K,V rows
        // Q projection fp32
        k_gemm<64,64,4,4><<<dim3(4, 7), 256, 0, stream>>>(
            qcur, wqkv, bqkv, nullptr, qbuf, Bz * NQ, D, D, 0);
        for (int b = 0; b < Bz; b++) {
            if (!instFull)
                k_input<<<Ni / 4, 256, 0, stream>>>(x, b * Ni, ip_w, ip_b, ip_g, ip_bb,
                                                    xm_w1, xm_b1, instb, nullptr);
            const u16* instp = instFull ? instb + (size_t)b * Ni * D : instb;
            for (int c0 = 0; c0 < Ni; c0 += kvRows) {
                mm_bf16<true><<<dim3(512 / 64, (kvRows + 63) / 64), 256, 0, stream>>>(
                    instp + (size_t)c0 * D, wkvb, bqkv + D, kvb, kvRows, 2 * D, D);
                k_xattn2<<<dim3(kvRows / SEGLEN, Hh), 128, 0, stream>>>(
                    qbuf, kvb, part, b, c0 / SEGLEN);
            }
            k_merge2<<<Hh * NQ, 256, 0, stream>>>(part, abuf, b);
        }
        // CA out-proj + pure residual
        k_gemm<64,64,4,4><<<dim3(4, 7), 256, 0, stream>>>(
            abuf, ca_wo + (size_t)i * D * D, ca_bo + (size_t)i * D, qcur, qtmp,
            Bz * NQ, D, D, 0);
        { float* t2 = qcur; qcur = qtmp; qtmp = t2; }
        // self-attention
        k_gemm<64,64,4,4><<<dim3(12, 7), 256, 0, stream>>>(
            qcur, sa_wqkv + (size_t)i * 3 * D * D, sa_bqkv + (size_t)i * 3 * D, nullptr, sqkv,
            Bz * NQ, 3 * D, D, 0);
        k_sattn<<<Bz * Hh, 128, 0, stream>>>(sqkv, abuf);
        k_gemm<64,64,4,4><<<dim3(4, 7), 256, 0, stream>>>(
            abuf, sa_wo + (size_t)i * D * D, sa_bo + (size_t)i * D, qcur, qtmp,
            Bz * NQ, D, D, 0);
        k_ln<<<Bz * NQ, 256, 0, stream>>>(qtmp, qtmp, sa_ln_g + i * D, sa_ln_b + i * D);
        { float* t2 = qcur; qcur = qtmp; qtmp = t2; }
        // FFN
        k_gemm<64,64,4,4><<<dim3(16, 7), 256, 0, stream>>>(
            qcur, ffn_w1 + (size_t)i * HIDd * D, ffn_b1 + (size_t)i * HIDd, nullptr, f1b,
            Bz * NQ, HIDd, D, 1);
        k_gemm<64,64,4,4><<<dim3(4, 7), 256, 0, stream>>>(
            f1b, ffn_w2 + (size_t)i * D * HIDd, ffn_b2 + (size_t)i * D, qcur, qtmp,
            Bz * NQ, D, HIDd, 0);
        k_ln<<<Bz * NQ, 256, 0, stream>>>(qtmp, qtmp, ffn_ln_g + i * D, ffn_ln_b + i * D);
        { float* t2 = qcur; qcur = qtmp; qtmp = t2; }
    }

    // final LN into qbuf (free now)
    float* qn = qbuf;
    k_ln<<<Bz * NQ, 256, 0, stream>>>(qcur, qn, out_ln_g, out_ln_b);
    // classification head -> d_out[0 .. 7600)
    k_gemm<64,64,4,4><<<dim3(4, 7), 256, 0, stream>>>(
        qn, cls_w1, cls_b1, nullptr, abuf, Bz * NQ, D, D, 1);
    k_gemm<64,64,4,4><<<dim3(1, 7), 256, 0, stream>>>(
        abuf, cls_w2, cls_b2, nullptr, out, Bz * NQ, NC1, D, 0);

    // mask path (inst/kv regions are dead now): h1 -> instb region, maskf -> kvb region
    k_cvt<<<128, 256, 0, stream>>>(qn, qnb, Bz * NQ * D);
    u16* h1b   = instb;   // Ni*D bf16 fits all tiers
    u16* maskf = kvb;     // Ni*D bf16 fits all tiers
    for (int b = 0; b < Bz; b++) {
        k_input<<<Ni / 4, 256, 0, stream>>>(x, b * Ni, ip_w, ip_b, ip_g, ip_bb,
                                            xm_w1, xm_b1, nullptr, h1b);
        mm_bf16<true><<<dim3(D / 64, (Ni + 63) / 64), 256, 0, stream>>>(
            h1b, xw2b, xm_b2, maskf, Ni, D, D);
        // pred_masks for batch b: qn_b(100x256) @ maskf(25000x256)^T
        mm_bf16<false><<<dim3((Ni + 63) / 64, (NQ + 63) / 64), 256, 0, stream>>>(
            qnb + (size_t)b * NQ * D, maskf, nullptr,
            out + Bz * NQ * NC1 + (size_t)b * NQ * Ni, NQ, Ni, D);
    }
}

// Round 5
// 3909.062 us; speedup vs baseline: 2.8791x; 1.6229x over previous
//
#include <hip/hip_runtime.h>

typedef unsigned short u16;
typedef unsigned int   u32;

// ---------------- problem constants ----------------
constexpr int Bz   = 4;
constexpr int Ni   = 25000;
constexpr int BNi  = Bz * Ni;      // 100000
constexpr int DIN  = 32;
constexpr int D    = 256;
constexpr int Hh   = 8;
constexpr int DH   = 32;
constexpr int Ll   = 6;
constexpr int NQ   = 100;
constexpr int NC1  = 19;
constexpr int HIDd = 1024;

constexpr int CHUNK  = 625;               // keys per flash block (divides 12500 & 25000)
constexpr int NCHUNK = Ni / CHUNK;        // 40
constexpr float SM_SCALE = 0.17677669529663687f;  // 1/sqrt(32)

// ---------------- bf16 helpers ----------------
__device__ __forceinline__ u16 f2b(float f) {
    union { float f; u32 u; } c; c.f = f;
    u32 u = c.u + 0x7FFFu + ((c.u >> 16) & 1u);
    return (u16)(u >> 16);
}
__device__ __forceinline__ float b2f(u16 h) {
    union { u32 u; float f; } c; c.u = ((u32)h) << 16;
    return c.f;
}

__global__ void k_cvt(const float* __restrict__ in, u16* __restrict__ out, int n) {
    for (int i = blockIdx.x * blockDim.x + threadIdx.x; i < n; i += gridDim.x * blockDim.x)
        out[i] = f2b(in[i]);
}

// ---------------- fused input projection (bf16 outputs) ----------------
__global__ __launch_bounds__(256) void k_input(
    const float* __restrict__ x, int row0,
    const float* __restrict__ ip_w, const float* __restrict__ ip_b,
    const float* __restrict__ ip_g, const float* __restrict__ ip_bb,
    const float* __restrict__ xw1, const float* __restrict__ xb1,
    u16* __restrict__ inst, u16* __restrict__ h1)
{
    constexpr int ROWS = 4;
    const int t  = threadIdx.x;
    const int r0 = blockIdx.x * ROWS;

    __shared__ float xs[ROWS][DIN];
    for (int idx = t; idx < ROWS * DIN; idx += 256)
        xs[idx / DIN][idx % DIN] = x[(size_t)(row0 + r0 + idx / DIN) * DIN + (idx % DIN)];
    __syncthreads();

    if (h1) {
        float wx[DIN];
        #pragma unroll
        for (int k = 0; k < DIN; k += 4) {
            float4 bv = *(const float4*)(xw1 + t * DIN + k);
            wx[k] = bv.x; wx[k+1] = bv.y; wx[k+2] = bv.z; wx[k+3] = bv.w;
        }
        const float bias = xb1[t];
        #pragma unroll
        for (int r = 0; r < ROWS; r++) {
            float a2 = bias;
            #pragma unroll
            for (int k = 0; k < DIN; k++) a2 += wx[k] * xs[r][k];
            h1[(size_t)(r0 + r) * D + t] = f2b(fmaxf(a2, 0.f));
        }
    }
    if (inst) {
        float wi[DIN];
        #pragma unroll
        for (int k = 0; k < DIN; k += 4) {
            float4 av = *(const float4*)(ip_w + t * DIN + k);
            wi[k] = av.x; wi[k+1] = av.y; wi[k+2] = av.z; wi[k+3] = av.w;
        }
        const float bias = ip_b[t];
        float y1[ROWS];
        #pragma unroll
        for (int r = 0; r < ROWS; r++) {
            float a1 = bias;
            #pragma unroll
            for (int k = 0; k < DIN; k++) a1 += wi[k] * xs[r][k];
            y1[r] = a1;
        }
        float s[ROWS], qs[ROWS];
        #pragma unroll
        for (int r = 0; r < ROWS; r++) { s[r] = y1[r]; qs[r] = y1[r] * y1[r]; }
        #pragma unroll
        for (int off = 32; off >= 1; off >>= 1) {
            #pragma unroll
            for (int r = 0; r < ROWS; r++) {
                s[r]  += __shfl_xor(s[r],  off);
                qs[r] += __shfl_xor(qs[r], off);
            }
        }
        __shared__ float red[2][4][ROWS];
        const int wid = t >> 6;
        if ((t & 63) == 0) {
            #pragma unroll
            for (int r = 0; r < ROWS; r++) { red[0][wid][r] = s[r]; red[1][wid][r] = qs[r]; }
        }
        __syncthreads();
        const float gg = ip_g[t], bb2 = ip_bb[t];
        #pragma unroll
        for (int r = 0; r < ROWS; r++) {
            float S = red[0][0][r] + red[0][1][r] + red[0][2][r] + red[0][3][r];
            float Q = red[1][0][r] + red[1][1][r] + red[1][2][r] + red[1][3][r];
            float m   = S * (1.f / D);
            float var = Q * (1.f / D) - m * m;
            float ri  = rsqrtf(var + 1e-5f);
            float val = (y1[r] - m) * ri * gg + bb2;
            inst[(size_t)(r0 + r) * D + t] = f2b(fmaxf(val, 0.f));
        }
    }
}

// ---------------- row LayerNorm ----------------
__global__ __launch_bounds__(256) void k_ln(
    const float* __restrict__ in, float* __restrict__ out,
    const float* __restrict__ g, const float* __restrict__ b)
{
    const int t = threadIdx.x;
    const int row = blockIdx.x;
    float v = in[(size_t)row * D + t];
    float s = v, q = v * v;
    #pragma unroll
    for (int off = 32; off >= 1; off >>= 1) { s += __shfl_xor(s, off); q += __shfl_xor(q, off); }
    __shared__ float red[2][4];
    const int wid = t >> 6;
    if ((t & 63) == 0) { red[0][wid] = s; red[1][wid] = q; }
    __syncthreads();
    float S = red[0][0] + red[0][1] + red[0][2] + red[0][3];
    float Q = red[1][0] + red[1][1] + red[1][2] + red[1][3];
    float m   = S * (1.f / D);
    float var = Q * (1.f / D) - m * m;
    float ri  = rsqrtf(var + 1e-5f);
    out[(size_t)row * D + t] = (v - m) * ri * g[t] + b[t];
}

// ---------------- broadcast query_embed ----------------
__global__ __launch_bounds__(256) void k_bcast(const float* __restrict__ qe, float* __restrict__ q)
{
    const int t = threadIdx.x;
    const int r = blockIdx.x;
    q[(size_t)r * D + t] = qe[(size_t)(r % NQ) * D + t];
}

// ---------------- fp32 tile GEMM (small ops) ----------------
template<int BM, int BN, int TM, int TN>
__global__ __launch_bounds__(256) void k_gemm(
    const float* __restrict__ A, const float* __restrict__ W,
    const float* __restrict__ bias, const float* __restrict__ resid,
    float* __restrict__ C, int M, int N, int K, int relu)
{
    constexpr int BK = 16;
    constexpr int TX = BN / TN, TY = BM / TM;
    static_assert(TX * TY == 256, "block must be 256 threads");
    __shared__ float As[BK][BM + 4];
    __shared__ float Ws[BK][BN + 4];

    const int tid = threadIdx.x;
    const int tx = tid % TX, ty = tid / TX;
    const int row0 = blockIdx.y * BM, col0 = blockIdx.x * BN;

    float acc[TM][TN];
    #pragma unroll
    for (int i = 0; i < TM; i++)
        #pragma unroll
        for (int j = 0; j < TN; j++) acc[i][j] = 0.f;

    for (int k0 = 0; k0 < K; k0 += BK) {
        __syncthreads();
        for (int idx = tid; idx < BM * (BK / 4); idx += 256) {
            int r = idx / (BK / 4), c4 = idx % (BK / 4);
            int gr = row0 + r;
            float4 v;
            if (gr < M) v = *(const float4*)(A + (size_t)gr * K + k0 + c4 * 4);
            else { v.x = v.y = v.z = v.w = 0.f; }
            As[c4*4+0][r] = v.x; As[c4*4+1][r] = v.y; As[c4*4+2][r] = v.z; As[c4*4+3][r] = v.w;
        }
        for (int idx = tid; idx < BN * (BK / 4); idx += 256) {
            int n = idx / (BK / 4), c4 = idx % (BK / 4);
            int gn = col0 + n;
            float4 v;
            if (gn < N) v = *(const float4*)(W + (size_t)gn * K + k0 + c4 * 4);
            else { v.x = v.y = v.z = v.w = 0.f; }
            Ws[c4*4+0][n] = v.x; Ws[c4*4+1][n] = v.y; Ws[c4*4+2][n] = v.z; Ws[c4*4+3][n] = v.w;
        }
        __syncthreads();
        #pragma unroll
        for (int kk = 0; kk < BK; kk++) {
            float a[TM], bb[TN];
            #pragma unroll
            for (int i = 0; i < TM; i++) a[i] = As[kk][ty * TM + i];
            #pragma unroll
            for (int j = 0; j < TN; j++) bb[j] = Ws[kk][tx * TN + j];
            #pragma unroll
            for (int i = 0; i < TM; i++)
                #pragma unroll
                for (int j = 0; j < TN; j++)
                    acc[i][j] = fmaf(a[i], bb[j], acc[i][j]);
        }
    }

    #pragma unroll
    for (int i = 0; i < TM; i++) {
        int gr = row0 + ty * TM + i;
        if (gr >= M) continue;
        #pragma unroll
        for (int j = 0; j < TN; j++) {
            int gn = col0 + tx * TN + j;
            if (gn >= N) continue;
            float v = acc[i][j];
            if (bias)  v += bias[gn];
            if (resid) v += resid[(size_t)gr * N + gn];
            if (relu)  v = fmaxf(v, 0.f);
            C[(size_t)gr * N + gn] = v;
        }
    }
}

// ---------------- bf16 MFMA types ----------------
typedef __attribute__((ext_vector_type(8))) __bf16 bf8v;
typedef __attribute__((ext_vector_type(8))) short  s8v;
typedef __attribute__((ext_vector_type(4))) float  f4v;

// ---------------- 128x128 MFMA GEMM: C = A(MxK) @ W(NxK)^T + bias ----------------
// 256 threads = 4 waves (2x2), each wave 64x64 via 4x4 mfma_f32_16x16x32_bf16.
// LDS pitch 40 bf16 (80B). Rows clamped on load, masked on store.
template<bool OUTBF>
__global__ __launch_bounds__(256) void mm128(
    const u16* __restrict__ A, const u16* __restrict__ W,
    const float* __restrict__ bias, void* __restrict__ Cv,
    int M, int N, int K)
{
    __shared__ u16 As[128 * 40];
    __shared__ u16 Bs[128 * 40];
    const int tid = threadIdx.x, lane = tid & 63, w = tid >> 6;
    const int wm = w >> 1, wn = w & 1;
    const int row0 = blockIdx.y * 128, col0 = blockIdx.x * 128;
    const int lr = lane & 15, hi = lane >> 4;

    f4v acc[4][4];
    #pragma unroll
    for (int i = 0; i < 4; i++)
        #pragma unroll
        for (int j = 0; j < 4; j++) acc[i][j] = (f4v){0.f, 0.f, 0.f, 0.f};

    for (int k0 = 0; k0 < K; k0 += 32) {
        __syncthreads();
        #pragma unroll
        for (int i = 0; i < 2; i++) {
            int idx = tid + i * 256;
            int r = idx >> 2, kc = idx & 3;
            int ga = min(row0 + r, M - 1);
            int gb = min(col0 + r, N - 1);
            *(uint4*)&As[r * 40 + kc * 8] = *(const uint4*)(A + (size_t)ga * K + k0 + kc * 8);
            *(uint4*)&Bs[r * 40 + kc * 8] = *(const uint4*)(W + (size_t)gb * K + k0 + kc * 8);
        }
        __syncthreads();
        bf8v a[4], bb[4];
        #pragma unroll
        for (int mi = 0; mi < 4; mi++)
            a[mi] = *(const bf8v*)&As[(wm * 64 + mi * 16 + lr) * 40 + hi * 8];
        #pragma unroll
        for (int ni = 0; ni < 4; ni++)
            bb[ni] = *(const bf8v*)&Bs[(wn * 64 + ni * 16 + lr) * 40 + hi * 8];
        #pragma unroll
        for (int mi = 0; mi < 4; mi++)
            #pragma unroll
            for (int ni = 0; ni < 4; ni++)
                acc[mi][ni] = __builtin_amdgcn_mfma_f32_16x16x32_bf16(a[mi], bb[ni], acc[mi][ni], 0, 0, 0);
    }

    const int crl = hi * 4, ccl = lr;
    #pragma unroll
    for (int mi = 0; mi < 4; mi++)
        #pragma unroll
        for (int ni = 0; ni < 4; ni++)
            #pragma unroll
            for (int r = 0; r < 4; r++) {
                int grow = row0 + wm * 64 + mi * 16 + crl + r;
                int gcol = col0 + wn * 64 + ni * 16 + ccl;
                if (grow < M && gcol < N) {
                    float v = acc[mi][ni][r];
                    if (bias) v += bias[gcol];
                    if (OUTBF) ((u16*)Cv)[(size_t)grow * N + gcol] = f2b(v);
                    else       ((float*)Cv)[(size_t)grow * N + gcol] = v;
                }
            }
}

// ---------------- MFMA flash cross-attention ----------------
// grid (Rloc/CHUNK, Hh), block 512 (8 waves x 16 queries). kv rows local: [K(256)|V(256)] bf16.
// Swapped QK: S = mfma(K_frag, Q_frag) -> S[key][q], q = lane&15 (softmax lane-local).
// P round-trips a per-wave LDS tile to become the PV A-operand; V transposed at stage time.
__global__ __launch_bounds__(512) void k_flash(
    const float* __restrict__ qbuf, const u16* __restrict__ kv,
    float* __restrict__ part, int b, int chunk0, int Rloc)
{
    const int tid = threadIdx.x;
    const int lane = tid & 63, w = tid >> 6;
    const int h = blockIdx.y;
    const int k0loc = blockIdx.x * CHUNK;
    const int lr = lane & 15, hi = lane >> 4;

    __shared__ u16 Ks[32 * 40];        // [key][d] pitch 40
    __shared__ u16 Vt[32 * 40];        // [d][key] pitch 40 (transposed)
    __shared__ u16 Pt[8][16 * 40];     // per-wave [q][key] pitch 40

    // Q fragment (B-operand): row=q=lr, k=d=hi*8..+8, pre-scaled
    const int qt = w * 16 + lr;
    const int qg = b * NQ + min(qt, NQ - 1);
    bf8v qf;
    {
        const float* Qp = qbuf + (size_t)qg * D + h * DH + hi * 8;
        union { s8v s; bf8v b; } qu;
        #pragma unroll
        for (int j = 0; j < 8; j++) qu.s[j] = (short)f2b(Qp[j] * SM_SCALE);
        qf = qu.b;
    }

    float m = -1e30f, l = 0.f;
    f4v o0 = (f4v){0.f,0.f,0.f,0.f}, o1 = (f4v){0.f,0.f,0.f,0.f};

    constexpr int NSTEP = (CHUNK + 31) / 32;   // 20
    for (int s = 0; s < NSTEP; s++) {
        const int ck = k0loc + s * 32;
        const int nv = min(32, k0loc + CHUNK - ck);   // 32 or 17 (last step)
        __syncthreads();
        if (tid < 128) {                 // stage K [key][d]
            int key = tid >> 2, g = tid & 3;
            int krow = min(ck + key, Rloc - 1);
            *(uint4*)&Ks[key * 40 + g * 8] =
                *(const uint4*)(kv + (size_t)krow * (2 * D) + h * DH + g * 8);
        } else if (tid < 256) {          // stage V transposed [d][key]
            int t2 = tid - 128;
            int key = t2 >> 2, g = t2 & 3;
            int krow = min(ck + key, Rloc - 1);
            uint4 u = *(const uint4*)(kv + (size_t)krow * (2 * D) + D + h * DH + g * 8);
            const u16* pu = (const u16*)&u;
            #pragma unroll
            for (int j = 0; j < 8; j++) Vt[(g * 8 + j) * 40 + key] = pu[j];
        }
        __syncthreads();

        // QK^T (swapped): S[key][q]
        bf8v kf0 = *(const bf8v*)&Ks[lr * 40 + hi * 8];
        bf8v kf1 = *(const bf8v*)&Ks[(16 + lr) * 40 + hi * 8];
        f4v s0 = (f4v){0.f,0.f,0.f,0.f}, s1 = (f4v){0.f,0.f,0.f,0.f};
        s0 = __builtin_amdgcn_mfma_f32_16x16x32_bf16(kf0, qf, s0, 0, 0, 0);
        s1 = __builtin_amdgcn_mfma_f32_16x16x32_bf16(kf1, qf, s1, 0, 0, 0);

        // mask invalid keys, per-q row max (within-lane + across the 4 lane-groups)
        float sv[8];
        #pragma unroll
        for (int r = 0; r < 4; r++) {
            int key0 = hi * 4 + r;
            sv[r]     = (key0 < nv)      ? s0[r] : -1e30f;
            sv[4 + r] = (16 + key0 < nv) ? s1[r] : -1e30f;
        }
        float smax = sv[0];
        #pragma unroll
        for (int j = 1; j < 8; j++) smax = fmaxf(smax, sv[j]);
        smax = fmaxf(smax, __shfl_xor(smax, 16));
        smax = fmaxf(smax, __shfl_xor(smax, 32));
        float mnew  = fmaxf(m, smax);
        float scale = __expf(m - mnew);
        m = mnew;

        float psum = 0.f;
        u16 pb[8];
        #pragma unroll
        for (int j = 0; j < 8; j++) {
            float p = __expf(sv[j] - mnew);
            psum += p;
            pb[j] = f2b(p);
        }
        psum += __shfl_xor(psum, 16);
        psum += __shfl_xor(psum, 32);
        l = l * scale + psum;

        // write P tile: row q=lr, keys hi*4+{0..3} and 16+hi*4+{0..3}
        u16* pw = &Pt[w][lr * 40];
        *(u32*)&pw[hi * 4]      = (u32)pb[0] | ((u32)pb[1] << 16);
        *(u32*)&pw[hi * 4 + 2]  = (u32)pb[2] | ((u32)pb[3] << 16);
        *(u32*)&pw[16 + hi * 4]     = (u32)pb[4] | ((u32)pb[5] << 16);
        *(u32*)&pw[16 + hi * 4 + 2] = (u32)pb[6] | ((u32)pb[7] << 16);

        // rescale O (factor per q' = hi*4 + r, fetched from lanes 0..15)
        const int qb4 = hi * 4;
        float f0 = __shfl(scale, qb4 + 0);
        float f1 = __shfl(scale, qb4 + 1);
        float f2 = __shfl(scale, qb4 + 2);
        float f3 = __shfl(scale, qb4 + 3);
        o0[0] *= f0; o0[1] *= f1; o0[2] *= f2; o0[3] *= f3;
        o1[0] *= f0; o1[1] *= f1; o1[2] *= f2; o1[3] *= f3;

        // PV: O[q][d] += P[q][keys] * V^T[d][keys]
        bf8v pf  = *(const bf8v*)&Pt[w][lr * 40 + hi * 8];
        bf8v vf0 = *(const bf8v*)&Vt[lr * 40 + hi * 8];
        bf8v vf1 = *(const bf8v*)&Vt[(16 + lr) * 40 + hi * 8];
        o0 = __builtin_amdgcn_mfma_f32_16x16x32_bf16(pf, vf0, o0, 0, 0, 0);
        o1 = __builtin_amdgcn_mfma_f32_16x16x32_bf16(pf, vf1, o1, 0, 0, 0);
    }

    // write partials: [m, l, acc32] per (h, chunk, qt)
    const size_t pbase = ((size_t)(h * NCHUNK + chunk0 + blockIdx.x) * 128) * 34;
    #pragma unroll
    for (int r = 0; r < 4; r++) {
        int qtr = w * 16 + hi * 4 + r;
        part[pbase + (size_t)qtr * 34 + 2 + lr]      = o0[r];
        part[pbase + (size_t)qtr * 34 + 2 + 16 + lr] = o1[r];
    }
    if (lane < 16) {
        part[pbase + (size_t)(w * 16 + lane) * 34 + 0] = m;
        part[pbase + (size_t)(w * 16 + lane) * 34 + 1] = l;
    }
}

// merge NCHUNK partials per (h,q) of batch b -> abuf (B*NQ, D)
__global__ __launch_bounds__(64) void k_fmerge(const float* __restrict__ part,
                                               float* __restrict__ abuf, int b)
{
    const int t = threadIdx.x;
    const int hq = blockIdx.x;                 // 0..Hh*NQ-1
    const int h = hq / NQ, q = hq % NQ;
    float mmax = -1e30f;
    for (int c = 0; c < NCHUNK; c++)
        mmax = fmaxf(mmax, part[((size_t)(h * NCHUNK + c) * 128 + q) * 34]);
    float L = 0.f, a = 0.f;
    for (int c = 0; c < NCHUNK; c++) {
        const float* p = &part[((size_t)(h * NCHUNK + c) * 128 + q) * 34];
        float wv = __expf(p[0] - mmax);
        L += wv * p[1];
        if (t < DH) a += wv * p[2 + t];
    }
    if (t < DH)
        abuf[((size_t)(b * NQ + q)) * D + h * DH + t] = a / L;
}

// ---------------- self-attention (100x100 per (b,h)) ----------------
__global__ __launch_bounds__(128) void k_sattn(const float* __restrict__ sqkv, float* __restrict__ abuf)
{
    const int tid = threadIdx.x;
    const int bh = blockIdx.x;
    const int b = bh >> 3, h = bh & 7;
    __shared__ float Ks[NQ][DH], Vs[NQ][DH];
    for (int idx = tid; idx < NQ * 8; idx += 128) {
        int kk = idx >> 3, f4 = idx & 7;
        const float* base = sqkv + ((size_t)(b * NQ + kk)) * (3 * D) + h * DH;
        *(float4*)&Ks[kk][f4 * 4] = *(const float4*)(base + D + f4 * 4);
        *(float4*)&Vs[kk][f4 * 4] = *(const float4*)(base + 2 * D + f4 * 4);
    }
    float qr[DH];
    const int q = tid;
    if (q < NQ) {
        const float* Qp = sqkv + ((size_t)(b * NQ + q)) * (3 * D) + h * DH;
        #pragma unroll
        for (int d = 0; d < DH; d += 4) {
            float4 v = *(const float4*)(Qp + d);
            qr[d] = v.x * SM_SCALE; qr[d+1] = v.y * SM_SCALE;
            qr[d+2] = v.z * SM_SCALE; qr[d+3] = v.w * SM_SCALE;
        }
    } else {
        #pragma unroll
        for (int d = 0; d < DH; d++) qr[d] = 0.f;
    }
    __syncthreads();
    float m = -1e30f, l = 0.f, acc[DH];
    #pragma unroll
    for (int d = 0; d < DH; d++) acc[d] = 0.f;
    for (int kk = 0; kk < NQ; kk++) {
        float sc = 0.f;
        #pragma unroll
        for (int d = 0; d < DH; d++) sc += qr[d] * Ks[kk][d];
        if (sc > m) {
            float r = __expf(m - sc);
            l *= r;
            #pragma unroll
            for (int d = 0; d < DH; d++) acc[d] *= r;
            m = sc;
        }
        float p = __expf(sc - m);
        l += p;
        #pragma unroll
        for (int d = 0; d < DH; d++) acc[d] += p * Vs[kk][d];
    }
    if (q < NQ) {
        float li = 1.f / l;
        float* o = abuf + ((size_t)(b * NQ + q)) * D + h * DH;
        #pragma unroll
        for (int d = 0; d < DH; d++) o[d] = acc[d] * li;
    }
}

// ---------------- host ----------------
extern "C" void kernel_launch(void* const* d_in, const int* in_sizes, int n_in,
                              void* d_out, int out_size, void* d_ws, size_t ws_size,
                              hipStream_t stream)
{
    const float* x        = (const float*)d_in[0];
    const float* ip_w     = (const float*)d_in[2];
    const float* ip_b     = (const float*)d_in[3];
    const float* ip_g     = (const float*)d_in[4];
    const float* ip_bb    = (const float*)d_in[5];
    const float* xm_w1    = (const float*)d_in[6];
    const float* xm_b1    = (const float*)d_in[7];
    const float* xm_w2    = (const float*)d_in[8];
    const float* xm_b2    = (const float*)d_in[9];
    const float* qe       = (const float*)d_in[10];
    const float* ca_wqkv  = (const float*)d_in[11];
    const float* ca_bqkv  = (const float*)d_in[12];
    const float* ca_wo    = (const float*)d_in[13];
    const float* ca_bo    = (const float*)d_in[14];
    const float* sa_wqkv  = (const float*)d_in[15];
    const float* sa_bqkv  = (const float*)d_in[16];
    const float* sa_wo    = (const float*)d_in[17];
    const float* sa_bo    = (const float*)d_in[18];
    const float* sa_ln_g  = (const float*)d_in[19];
    const float* sa_ln_b  = (const float*)d_in[20];
    const float* ffn_w1   = (const float*)d_in[21];
    const float* ffn_b1   = (const float*)d_in[22];
    const float* ffn_w2   = (const float*)d_in[23];
    const float* ffn_b2   = (const float*)d_in[24];
    const float* ffn_ln_g = (const float*)d_in[25];
    const float* ffn_ln_b = (const float*)d_in[26];
    const float* out_ln_g = (const float*)d_in[27];
    const float* out_ln_b = (const float*)d_in[28];
    const float* cls_w1   = (const float*)d_in[29];
    const float* cls_b1   = (const float*)d_in[30];
    const float* cls_w2   = (const float*)d_in[31];
    const float* cls_b2   = (const float*)d_in[32];
    float* out = (float*)d_out;

    // ---- workspace tiering (bytes; exact need ~89.6/51.2/38.4 MB + slack) ----
    const size_t needA = 92000000ull;
    const size_t needB = 54000000ull;
    const size_t needC = 41000000ull;
    int instRows, kvRows;
    if      (ws_size >= needA) { instRows = BNi; kvRows = Ni;    }
    else if (ws_size >= needB) { instRows = Ni;  kvRows = Ni;    }
    else if (ws_size >= needC) { instRows = Ni;  kvRows = 12500; }
    else return;
    const bool instFull = (instRows == BNi);

    char* wp = (char*)d_ws;
    auto alloc = [&](size_t bytes) -> char* {
        char* r = wp; wp += (bytes + 255) & ~(size_t)255; return r;
    };
    u16*   instb = (u16*)  alloc((size_t)instRows * D * 2);
    u16*   kvb   = (u16*)  alloc((size_t)kvRows * 2 * D * 2);
    float* part  = (float*)alloc((size_t)Hh * NCHUNK * 128 * 34 * 4);   // 5.57 MB
    float* qbuf  = (float*)alloc(409600);
    float* abuf  = (float*)alloc(409600);
    float* sqkv  = (float*)alloc(1228800);
    float* f1b   = (float*)alloc(1638400);
    float* qA    = (float*)alloc(409600);
    float* qB    = (float*)alloc(409600);
    u16*   wqkvb = (u16*)  alloc((size_t)Ll * 3 * D * D * 2);
    u16*   xw2b  = (u16*)  alloc((size_t)D * D * 2);
    u16*   qnb   = (u16*)  alloc((size_t)Bz * NQ * D * 2);

    k_cvt<<<1024, 256, 0, stream>>>(ca_wqkv, wqkvb, Ll * 3 * D * D);
    k_cvt<<<64,   256, 0, stream>>>(xm_w2, xw2b, D * D);

    if (instFull)
        k_input<<<BNi / 4, 256, 0, stream>>>(x, 0, ip_w, ip_b, ip_g, ip_bb,
                                             xm_w1, xm_b1, instb, nullptr);
    k_bcast<<<Bz * NQ, 256, 0, stream>>>(qe, qA);

    float* qcur = qA;
    float* qtmp = qB;
    for (int i = 0; i < Ll; i++) {
        const float* wqkv = ca_wqkv + (size_t)i * 3 * D * D;
        const float* bqkv = ca_bqkv + (size_t)i * 3 * D;
        const u16*   wkvb = wqkvb + (size_t)i * 3 * D * D + (size_t)D * D;  // K,V rows
        // Q projection fp32
        k_gemm<64,64,4,4><<<dim3(4, 7), 256, 0, stream>>>(
            qcur, wqkv, bqkv, nullptr, qbuf, Bz * NQ, D, D, 0);
        for (int b = 0; b < Bz; b++) {
            if (!instFull)
                k_input<<<Ni / 4, 256, 0, stream>>>(x, b * Ni, ip_w, ip_b, ip_g, ip_bb,
                                                    xm_w1, xm_b1, instb, nullptr);
            const u16* instp = instFull ? instb + (size_t)b * Ni * D : instb;
            for (int c0 = 0; c0 < Ni; c0 += kvRows) {
                const int R = kvRows;
                mm128<true><<<dim3(512 / 128, (R + 127) / 128), 256, 0, stream>>>(
                    instp + (size_t)c0 * D, wkvb, bqkv + D, kvb, R, 2 * D, D);
                k_flash<<<dim3(R / CHUNK, Hh), 512, 0, stream>>>(
                    qbuf, kvb, part, b, c0 / CHUNK, R);
            }
            k_fmerge<<<Hh * NQ, 64, 0, stream>>>(part, abuf, b);
        }
        // CA out-proj + pure residual
        k_gemm<64,64,4,4><<<dim3(4, 7), 256, 0, stream>>>(
            abuf, ca_wo + (size_t)i * D * D, ca_bo + (size_t)i * D, qcur, qtmp,
            Bz * NQ, D, D, 0);
        { float* t2 = qcur; qcur = qtmp; qtmp = t2; }
        // self-attention
        k_gemm<64,64,4,4><<<dim3(12, 7), 256, 0, stream>>>(
            qcur, sa_wqkv + (size_t)i * 3 * D * D, sa_bqkv + (size_t)i * 3 * D, nullptr, sqkv,
            Bz * NQ, 3 * D, D, 0);
        k_sattn<<<Bz * Hh, 128, 0, stream>>>(sqkv, abuf);
        k_gemm<64,64,4,4><<<dim3(4, 7), 256, 0, stream>>>(
            abuf, sa_wo + (size_t)i * D * D, sa_bo + (size_t)i * D, qcur, qtmp,
            Bz * NQ, D, D, 0);
        k_ln<<<Bz * NQ, 256, 0, stream>>>(qtmp, qtmp, sa_ln_g + i * D, sa_ln_b + i * D);
        { float* t2 = qcur; qcur = qtmp; qtmp = t2; }
        // FFN
        k_gemm<64,64,4,4><<<dim3(16, 7), 256, 0, stream>>>(
            qcur, ffn_w1 + (size_t)i * HIDd * D, ffn_b1 + (size_t)i * HIDd, nullptr, f1b,
            Bz * NQ, HIDd, D, 1);
        k_gemm<64,64,4,4><<<dim3(4, 7), 256, 0, stream>>>(
            f1b, ffn_w2 + (size_t)i * D * HIDd, ffn_b2 + (size_t)i * D, qcur, qtmp,
            Bz * NQ, D, HIDd, 0);
        k_ln<<<Bz * NQ, 256, 0, stream>>>(qtmp, qtmp, ffn_ln_g + i * D, ffn_ln_b + i * D);
        { float* t2 = qcur; qcur = qtmp; qtmp = t2; }
    }

    // final LN into qbuf (free now)
    float* qn = qbuf;
    k_ln<<<Bz * NQ, 256, 0, stream>>>(qcur, qn, out_ln_g, out_ln_b);
    // classification head -> d_out[0 .. 7600)
    k_gemm<64,64,4,4><<<dim3(4, 7), 256, 0, stream>>>(
        qn, cls_w1, cls_b1, nullptr, abuf, Bz * NQ, D, D, 1);
    k_gemm<64,64,4,4><<<dim3(1, 7), 256, 0, stream>>>(
        abuf, cls_w2, cls_b2, nullptr, out, Bz * NQ, NC1, D, 0);

    // mask path (inst/kv regions dead now)
    k_cvt<<<128, 256, 0, stream>>>(qn, qnb, Bz * NQ * D);
    u16* h1b   = instb;
    u16* maskf = kvb;
    for (int b = 0; b < Bz; b++) {
        k_input<<<Ni / 4, 256, 0, stream>>>(x, b * Ni, ip_w, ip_b, ip_g, ip_bb,
                                            xm_w1, xm_b1, nullptr, h1b);
        mm128<true><<<dim3(D / 128, (Ni + 127) / 128), 256, 0, stream>>>(
            h1b, xw2b, xm_b2, maskf, Ni, D, D);
        // pred_masks: qn_b(100x256) @ maskf(25000x256)^T -> fp32 out
        mm128<false><<<dim3((Ni + 127) / 128, 1), 256, 0, stream>>>(
            qnb + (size_t)b * NQ * D, maskf, nullptr,
            out + Bz * NQ * NC1 + (size_t)b * NQ * Ni, NQ, Ni, D);
    }
}

// Round 6
// 1991.683 us; speedup vs baseline: 5.6509x; 1.9627x over previous
//
#include <hip/hip_runtime.h>

typedef unsigned short u16;
typedef unsigned int   u32;

// ---------------- problem constants ----------------
constexpr int Bz   = 4;
constexpr int Ni   = 25000;
constexpr int BNi  = Bz * Ni;      // 100000
constexpr int DIN  = 32;
constexpr int D    = 256;
constexpr int Hh   = 8;
constexpr int DH   = 32;
constexpr int Ll   = 6;
constexpr int NQ   = 100;
constexpr int NC1  = 19;
constexpr int HIDd = 1024;

constexpr int CHUNK  = 625;
constexpr int NCHUNK = Ni / CHUNK;        // 40
constexpr size_t PARTB = (size_t)Hh * NCHUNK * 128 * 34;   // floats per batch
constexpr float SM_SCALE = 0.17677669529663687f;  // 1/sqrt(32)

// ---------------- bf16 helpers ----------------
__device__ __forceinline__ u16 f2b(float f) {
    union { float f; u32 u; } c; c.f = f;
    u32 u = c.u + 0x7FFFu + ((c.u >> 16) & 1u);
    return (u16)(u >> 16);
}

__global__ void k_cvt(const float* __restrict__ in, u16* __restrict__ out, int n) {
    for (int i = blockIdx.x * blockDim.x + threadIdx.x; i < n; i += gridDim.x * blockDim.x)
        out[i] = f2b(in[i]);
}

// ---------------- MFMA types ----------------
typedef __attribute__((ext_vector_type(8))) __bf16 bf8v;
typedef __attribute__((ext_vector_type(8))) short  s8v;
typedef __attribute__((ext_vector_type(4))) float  f4v;

// ---------------- MFMA input projection ----------------
// out = relu([LN](x @ w^T + bias)) as bf16. x fp32 (rows row0+r), w16 bf16 256x32.
// 512 thr = 8 waves; wave w owns rows blk*128+w*16..+16, all 256 cols.
// Swapped operands: D[c][r] = mfma(Wfrag(c), Xfrag(r)) -> lane holds row r=lane&15,
// cols c = ci*16 + (lane>>4)*4 + reg -> LN per row via 2 shfl_xor.
template<bool DOLN>
__global__ __launch_bounds__(512) void k_inproj(
    const float* __restrict__ x, int row0, int Mloc,
    const u16* __restrict__ w16, const float* __restrict__ bias,
    const float* __restrict__ g, const float* __restrict__ bb,
    u16* __restrict__ outb)
{
    __shared__ u16 Ws[256 * 40];
    __shared__ float Cb[256], Cg[256], Cbb[256];
    const int tid = threadIdx.x, lane = tid & 63, w = tid >> 6;
    const int lr = lane & 15, hi = lane >> 4;

    for (int ch = tid; ch < 1024; ch += 512) {
        int r = ch >> 2, g4 = ch & 3;
        *(uint4*)&Ws[r * 40 + g4 * 8] = *(const uint4*)(w16 + r * 32 + g4 * 8);
    }
    if (tid < 256) {
        Cb[tid] = bias[tid];
        if (DOLN) { Cg[tid] = g[tid]; Cbb[tid] = bb[tid]; }
    }

    const int rloc = blockIdx.x * 128 + w * 16 + lr;
    const int gr = row0 + min(rloc, Mloc - 1);
    bf8v xf;
    {
        const float* xp = x + (size_t)gr * DIN + hi * 8;
        float4 a = *(const float4*)xp, c = *(const float4*)(xp + 4);
        union { s8v s; bf8v b; } u;
        u.s[0] = (short)f2b(a.x); u.s[1] = (short)f2b(a.y);
        u.s[2] = (short)f2b(a.z); u.s[3] = (short)f2b(a.w);
        u.s[4] = (short)f2b(c.x); u.s[5] = (short)f2b(c.y);
        u.s[6] = (short)f2b(c.z); u.s[7] = (short)f2b(c.w);
        xf = u.b;
    }
    __syncthreads();

    f4v acc[16];
    #pragma unroll
    for (int ci = 0; ci < 16; ci++) {
        acc[ci] = (f4v){0.f, 0.f, 0.f, 0.f};
        bf8v af = *(const bf8v*)&Ws[(ci * 16 + lr) * 40 + hi * 8];
        acc[ci] = __builtin_amdgcn_mfma_f32_16x16x32_bf16(af, xf, acc[ci], 0, 0, 0);
    }
    // add bias
    #pragma unroll
    for (int ci = 0; ci < 16; ci++)
        #pragma unroll
        for (int r = 0; r < 4; r++)
            acc[ci][r] += Cb[ci * 16 + hi * 4 + r];

    float mean = 0.f, ri = 1.f;
    if (DOLN) {
        float s = 0.f, q = 0.f;
        #pragma unroll
        for (int ci = 0; ci < 16; ci++)
            #pragma unroll
            for (int r = 0; r < 4; r++) { s += acc[ci][r]; q += acc[ci][r] * acc[ci][r]; }
        s += __shfl_xor(s, 16); s += __shfl_xor(s, 32);
        q += __shfl_xor(q, 16); q += __shfl_xor(q, 32);
        mean = s * (1.f / D);
        float var = q * (1.f / D) - mean * mean;
        ri = rsqrtf(var + 1e-5f);
    }
    if (rloc < Mloc) {
        #pragma unroll
        for (int ci = 0; ci < 16; ci++) {
            u16 o[4];
            #pragma unroll
            for (int r = 0; r < 4; r++) {
                float v = acc[ci][r];
                if (DOLN) v = (v - mean) * ri * Cg[ci * 16 + hi * 4 + r] + Cbb[ci * 16 + hi * 4 + r];
                o[r] = f2b(fmaxf(v, 0.f));
            }
            uint2 pk;
            pk.x = (u32)o[0] | ((u32)o[1] << 16);
            pk.y = (u32)o[2] | ((u32)o[3] << 16);
            *(uint2*)&outb[(size_t)rloc * 256 + ci * 16 + hi * 4] = pk;
        }
    }
}

// ---------------- row LayerNorm ----------------
__global__ __launch_bounds__(256) void k_ln(
    const float* __restrict__ in, float* __restrict__ out,
    const float* __restrict__ g, const float* __restrict__ b)
{
    const int t = threadIdx.x;
    const int row = blockIdx.x;
    float v = in[(size_t)row * D + t];
    float s = v, q = v * v;
    #pragma unroll
    for (int off = 32; off >= 1; off >>= 1) { s += __shfl_xor(s, off); q += __shfl_xor(q, off); }
    __shared__ float red[2][4];
    const int wid = t >> 6;
    if ((t & 63) == 0) { red[0][wid] = s; red[1][wid] = q; }
    __syncthreads();
    float S = red[0][0] + red[0][1] + red[0][2] + red[0][3];
    float Q = red[1][0] + red[1][1] + red[1][2] + red[1][3];
    float m   = S * (1.f / D);
    float var = Q * (1.f / D) - m * m;
    float ri  = rsqrtf(var + 1e-5f);
    out[(size_t)row * D + t] = (v - m) * ri * g[t] + b[t];
}

__global__ __launch_bounds__(256) void k_bcast(const float* __restrict__ qe, float* __restrict__ q)
{
    const int t = threadIdx.x;
    const int r = blockIdx.x;
    q[(size_t)r * D + t] = qe[(size_t)(r % NQ) * D + t];
}

// ---------------- fp32 tile GEMM (cls head only) ----------------
template<int BM, int BN, int TM, int TN>
__global__ __launch_bounds__(256) void k_gemm(
    const float* __restrict__ A, const float* __restrict__ W,
    const float* __restrict__ bias, const float* __restrict__ resid,
    float* __restrict__ C, int M, int N, int K, int relu)
{
    constexpr int BK = 16;
    constexpr int TX = BN / TN, TY = BM / TM;
    static_assert(TX * TY == 256, "block must be 256 threads");
    __shared__ float As[BK][BM + 4];
    __shared__ float Ws[BK][BN + 4];

    const int tid = threadIdx.x;
    const int tx = tid % TX, ty = tid / TX;
    const int row0 = blockIdx.y * BM, col0 = blockIdx.x * BN;

    float acc[TM][TN];
    #pragma unroll
    for (int i = 0; i < TM; i++)
        #pragma unroll
        for (int j = 0; j < TN; j++) acc[i][j] = 0.f;

    for (int k0 = 0; k0 < K; k0 += BK) {
        __syncthreads();
        for (int idx = tid; idx < BM * (BK / 4); idx += 256) {
            int r = idx / (BK / 4), c4 = idx % (BK / 4);
            int gr = row0 + r;
            float4 v;
            if (gr < M) v = *(const float4*)(A + (size_t)gr * K + k0 + c4 * 4);
            else { v.x = v.y = v.z = v.w = 0.f; }
            As[c4*4+0][r] = v.x; As[c4*4+1][r] = v.y; As[c4*4+2][r] = v.z; As[c4*4+3][r] = v.w;
        }
        for (int idx = tid; idx < BN * (BK / 4); idx += 256) {
            int n = idx / (BK / 4), c4 = idx % (BK / 4);
            int gn = col0 + n;
            float4 v;
            if (gn < N) v = *(const float4*)(W + (size_t)gn * K + k0 + c4 * 4);
            else { v.x = v.y = v.z = v.w = 0.f; }
            Ws[c4*4+0][n] = v.x; Ws[c4*4+1][n] = v.y; Ws[c4*4+2][n] = v.z; Ws[c4*4+3][n] = v.w;
        }
        __syncthreads();
        #pragma unroll
        for (int kk = 0; kk < BK; kk++) {
            float a[TM], bb[TN];
            #pragma unroll
            for (int i = 0; i < TM; i++) a[i] = As[kk][ty * TM + i];
            #pragma unroll
            for (int j = 0; j < TN; j++) bb[j] = Ws[kk][tx * TN + j];
            #pragma unroll
            for (int i = 0; i < TM; i++)
                #pragma unroll
                for (int j = 0; j < TN; j++)
                    acc[i][j] = fmaf(a[i], bb[j], acc[i][j]);
        }
    }

    #pragma unroll
    for (int i = 0; i < TM; i++) {
        int gr = row0 + ty * TM + i;
        if (gr >= M) continue;
        #pragma unroll
        for (int j = 0; j < TN; j++) {
            int gn = col0 + tx * TN + j;
            if (gn >= N) continue;
            float v = acc[i][j];
            if (bias)  v += bias[gn];
            if (resid) v += resid[(size_t)gr * N + gn];
            if (relu)  v = fmaxf(v, 0.f);
            C[(size_t)gr * N + gn] = v;
        }
    }
}

// ---------------- mm_small: bf16 MFMA GEMM, fp32 A (converted in staging), fp32 out ----
// C = A(MxK fp32) @ W(NxK bf16)^T + bias (+resid) (+relu). 64x64 tile, 4 waves.
template<bool RELU>
__global__ __launch_bounds__(256) void mm_small(
    const float* __restrict__ A, const u16* __restrict__ W,
    const float* __restrict__ bias, const float* __restrict__ resid,
    float* __restrict__ C, int M, int N, int K)
{
    __shared__ u16 As[64 * 40];
    __shared__ u16 Bs[64 * 40];
    const int tid  = threadIdx.x;
    const int lane = tid & 63, w = tid >> 6;
    const int wm = w >> 1, wn = w & 1;
    const int row0 = blockIdx.y * 64, col0 = blockIdx.x * 64;
    const int lr = lane & 15, hi = lane >> 4;

    f4v acc[2][2];
    #pragma unroll
    for (int i = 0; i < 2; i++)
        #pragma unroll
        for (int j = 0; j < 2; j++) acc[i][j] = (f4v){0.f, 0.f, 0.f, 0.f};

    const int sr = tid >> 2, sc = (tid & 3) * 8;
    const int ga = min(row0 + sr, M - 1);
    const int gw = min(col0 + sr, N - 1);

    for (int k0 = 0; k0 < K; k0 += 32) {
        __syncthreads();
        {
            const float* ap = A + (size_t)ga * K + k0 + sc;
            float4 a = *(const float4*)ap, c = *(const float4*)(ap + 4);
            union { s8v s; uint4 u; } cv;
            cv.s[0] = (short)f2b(a.x); cv.s[1] = (short)f2b(a.y);
            cv.s[2] = (short)f2b(a.z); cv.s[3] = (short)f2b(a.w);
            cv.s[4] = (short)f2b(c.x); cv.s[5] = (short)f2b(c.y);
            cv.s[6] = (short)f2b(c.z); cv.s[7] = (short)f2b(c.w);
            *(uint4*)&As[sr * 40 + sc] = cv.u;
            *(uint4*)&Bs[sr * 40 + sc] = *(const uint4*)(W + (size_t)gw * K + k0 + sc);
        }
        __syncthreads();
        bf8v a0 = *(const bf8v*)&As[(wm * 32      + lr) * 40 + hi * 8];
        bf8v a1 = *(const bf8v*)&As[(wm * 32 + 16 + lr) * 40 + hi * 8];
        bf8v b0 = *(const bf8v*)&Bs[(wn * 32      + lr) * 40 + hi * 8];
        bf8v b1 = *(const bf8v*)&Bs[(wn * 32 + 16 + lr) * 40 + hi * 8];
        acc[0][0] = __builtin_amdgcn_mfma_f32_16x16x32_bf16(a0, b0, acc[0][0], 0, 0, 0);
        acc[0][1] = __builtin_amdgcn_mfma_f32_16x16x32_bf16(a0, b1, acc[0][1], 0, 0, 0);
        acc[1][0] = __builtin_amdgcn_mfma_f32_16x16x32_bf16(a1, b0, acc[1][0], 0, 0, 0);
        acc[1][1] = __builtin_amdgcn_mfma_f32_16x16x32_bf16(a1, b1, acc[1][1], 0, 0, 0);
    }

    const int crl = hi * 4, ccl = lr;
    #pragma unroll
    for (int mi = 0; mi < 2; mi++)
        #pragma unroll
        for (int ni = 0; ni < 2; ni++)
            #pragma unroll
            for (int r = 0; r < 4; r++) {
                int grow = row0 + wm * 32 + mi * 16 + crl + r;
                int gcol = col0 + wn * 32 + ni * 16 + ccl;
                if (grow < M && gcol < N) {
                    float v = acc[mi][ni][r];
                    if (bias)  v += bias[gcol];
                    if (resid) v += resid[(size_t)grow * N + gcol];
                    if (RELU)  v = fmaxf(v, 0.f);
                    C[(size_t)grow * N + gcol] = v;
                }
            }
}

// ---------------- mm128: bf16 MFMA GEMM 128x128, z-strided ----------------
template<bool OUTBF>
__global__ __launch_bounds__(256) void mm128(
    const u16* __restrict__ A, const u16* __restrict__ W,
    const float* __restrict__ bias, void* __restrict__ Cv,
    int M, int N, int K, long long sA, long long sW, long long sC)
{
    __shared__ u16 As[128 * 40];
    __shared__ u16 Bs[128 * 40];
    A += (size_t)blockIdx.z * sA;
    W += (size_t)blockIdx.z * sW;
    const int tid = threadIdx.x, lane = tid & 63, w = tid >> 6;
    const int wm = w >> 1, wn = w & 1;
    const int row0 = blockIdx.y * 128, col0 = blockIdx.x * 128;
    const int lr = lane & 15, hi = lane >> 4;

    f4v acc[4][4];
    #pragma unroll
    for (int i = 0; i < 4; i++)
        #pragma unroll
        for (int j = 0; j < 4; j++) acc[i][j] = (f4v){0.f, 0.f, 0.f, 0.f};

    for (int k0 = 0; k0 < K; k0 += 32) {
        __syncthreads();
        #pragma unroll
        for (int i = 0; i < 2; i++) {
            int idx = tid + i * 256;
            int r = idx >> 2, kc = idx & 3;
            int ga = min(row0 + r, M - 1);
            int gb = min(col0 + r, N - 1);
            *(uint4*)&As[r * 40 + kc * 8] = *(const uint4*)(A + (size_t)ga * K + k0 + kc * 8);
            *(uint4*)&Bs[r * 40 + kc * 8] = *(const uint4*)(W + (size_t)gb * K + k0 + kc * 8);
        }
        __syncthreads();
        bf8v a[4], bb[4];
        #pragma unroll
        for (int mi = 0; mi < 4; mi++)
            a[mi] = *(const bf8v*)&As[(wm * 64 + mi * 16 + lr) * 40 + hi * 8];
        #pragma unroll
        for (int ni = 0; ni < 4; ni++)
            bb[ni] = *(const bf8v*)&Bs[(wn * 64 + ni * 16 + lr) * 40 + hi * 8];
        #pragma unroll
        for (int mi = 0; mi < 4; mi++)
            #pragma unroll
            for (int ni = 0; ni < 4; ni++)
                acc[mi][ni] = __builtin_amdgcn_mfma_f32_16x16x32_bf16(a[mi], bb[ni], acc[mi][ni], 0, 0, 0);
    }

    const int crl = hi * 4, ccl = lr;
    #pragma unroll
    for (int mi = 0; mi < 4; mi++)
        #pragma unroll
        for (int ni = 0; ni < 4; ni++)
            #pragma unroll
            for (int r = 0; r < 4; r++) {
                int grow = row0 + wm * 64 + mi * 16 + crl + r;
                int gcol = col0 + wn * 64 + ni * 16 + ccl;
                if (grow < M && gcol < N) {
                    float v = acc[mi][ni][r];
                    if (bias) v += bias[gcol];
                    if (OUTBF) ((u16*)Cv)[(size_t)blockIdx.z * sC + (size_t)grow * N + gcol] = f2b(v);
                    else       ((float*)Cv)[(size_t)blockIdx.z * sC + (size_t)grow * N + gcol] = v;
                }
            }
}

// ---------------- MFMA flash cross-attention (64-key steps, z-batched) ----------------
__global__ __launch_bounds__(512) void k_flash(
    const float* __restrict__ qbuf, const u16* __restrict__ kv,
    float* __restrict__ part, int bBase, size_t kvStride, size_t pStride)
{
    const int tid = threadIdx.x;
    const int lane = tid & 63, w = tid >> 6;
    const int h = blockIdx.y;
    const int b = bBase + blockIdx.z;
    const u16* kvp = kv + (size_t)blockIdx.z * kvStride;
    float* pp = part + (size_t)blockIdx.z * pStride;
    const int k0loc = blockIdx.x * CHUNK;
    const int lr = lane & 15, hi = lane >> 4;

    __shared__ u16 Ks[64 * 40];        // [key][d]
    __shared__ u16 Vt[32 * 72];        // [d][key] transposed
    __shared__ u16 Pt[8][16 * 72];     // per-wave [q][key]

    const int qt = w * 16 + lr;
    const int qg = b * NQ + min(qt, NQ - 1);
    bf8v qf;
    {
        const float* Qp = qbuf + (size_t)qg * D + h * DH + hi * 8;
        union { s8v s; bf8v b; } qu;
        #pragma unroll
        for (int j = 0; j < 8; j++) qu.s[j] = (short)f2b(Qp[j] * SM_SCALE);
        qf = qu.b;
    }

    float m = -1e30f, l = 0.f;
    f4v o0 = (f4v){0.f,0.f,0.f,0.f}, o1 = (f4v){0.f,0.f,0.f,0.f};

    constexpr int NSTEP = (CHUNK + 63) / 64;   // 10
    for (int s = 0; s < NSTEP; s++) {
        const int ck = k0loc + s * 64;
        const int nv = min(64, k0loc + CHUNK - ck);   // 64 or 49
        __syncthreads();
        if (tid < 256) {                 // stage K [key][d], 64 rows
            int key = tid >> 2, g = tid & 3;
            int krow = min(ck + key, Ni - 1);
            *(uint4*)&Ks[key * 40 + g * 8] =
                *(const uint4*)(kvp + (size_t)krow * (2 * D) + h * DH + g * 8);
        } else {                          // stage V transposed [d][key]
            int t2 = tid - 256;
            int key = t2 >> 2, g = t2 & 3;
            int krow = min(ck + key, Ni - 1);
            uint4 u = *(const uint4*)(kvp + (size_t)krow * (2 * D) + D + h * DH + g * 8);
            const u16* pu = (const u16*)&u;
            #pragma unroll
            for (int j = 0; j < 8; j++) Vt[(g * 8 + j) * 72 + key] = pu[j];
        }
        __syncthreads();

        // QK^T (swapped): S[key][q], 4 key-frags
        f4v sf[4];
        #pragma unroll
        for (int j = 0; j < 4; j++) {
            bf8v kf = *(const bf8v*)&Ks[(j * 16 + lr) * 40 + hi * 8];
            sf[j] = (f4v){0.f,0.f,0.f,0.f};
            sf[j] = __builtin_amdgcn_mfma_f32_16x16x32_bf16(kf, qf, sf[j], 0, 0, 0);
        }

        float sv[16];
        #pragma unroll
        for (int j = 0; j < 4; j++)
            #pragma unroll
            for (int r = 0; r < 4; r++) {
                int key0 = j * 16 + hi * 4 + r;
                sv[j * 4 + r] = (key0 < nv) ? sf[j][r] : -1e30f;
            }
        float smax = sv[0];
        #pragma unroll
        for (int j = 1; j < 16; j++) smax = fmaxf(smax, sv[j]);
        smax = fmaxf(smax, __shfl_xor(smax, 16));
        smax = fmaxf(smax, __shfl_xor(smax, 32));
        float mnew  = fmaxf(m, smax);
        float scale = __expf(m - mnew);
        m = mnew;

        float psum = 0.f;
        u16 pb[16];
        #pragma unroll
        for (int j = 0; j < 16; j++) {
            float p = __expf(sv[j] - mnew);
            psum += p;
            pb[j] = f2b(p);
        }
        psum += __shfl_xor(psum, 16);
        psum += __shfl_xor(psum, 32);
        l = l * scale + psum;

        u16* pw = &Pt[w][lr * 72];
        #pragma unroll
        for (int j = 0; j < 4; j++) {
            *(u32*)&pw[j * 16 + hi * 4]     = (u32)pb[j*4+0] | ((u32)pb[j*4+1] << 16);
            *(u32*)&pw[j * 16 + hi * 4 + 2] = (u32)pb[j*4+2] | ((u32)pb[j*4+3] << 16);
        }

        const int qb4 = hi * 4;
        float f0 = __shfl(scale, qb4 + 0);
        float f1 = __shfl(scale, qb4 + 1);
        float f2 = __shfl(scale, qb4 + 2);
        float f3 = __shfl(scale, qb4 + 3);
        o0[0] *= f0; o0[1] *= f1; o0[2] *= f2; o0[3] *= f3;
        o1[0] *= f0; o1[1] *= f1; o1[2] *= f2; o1[3] *= f3;

        // PV over 64 keys = 2 K=32 chunks
        #pragma unroll
        for (int j = 0; j < 2; j++) {
            bf8v pf  = *(const bf8v*)&Pt[w][lr * 72 + j * 32 + hi * 8];
            bf8v vf0 = *(const bf8v*)&Vt[lr * 72 + j * 32 + hi * 8];
            bf8v vf1 = *(const bf8v*)&Vt[(16 + lr) * 72 + j * 32 + hi * 8];
            o0 = __builtin_amdgcn_mfma_f32_16x16x32_bf16(pf, vf0, o0, 0, 0, 0);
            o1 = __builtin_amdgcn_mfma_f32_16x16x32_bf16(pf, vf1, o1, 0, 0, 0);
        }
    }

    const size_t pbase = ((size_t)(h * NCHUNK + blockIdx.x) * 128) * 34;
    #pragma unroll
    for (int r = 0; r < 4; r++) {
        int qtr = w * 16 + hi * 4 + r;
        pp[pbase + (size_t)qtr * 34 + 2 + lr]      = o0[r];
        pp[pbase + (size_t)qtr * 34 + 2 + 16 + lr] = o1[r];
    }
    if (lane < 16) {
        pp[pbase + (size_t)(w * 16 + lane) * 34 + 0] = m;
        pp[pbase + (size_t)(w * 16 + lane) * 34 + 1] = l;
    }
}

__global__ __launch_bounds__(64) void k_fmerge(const float* __restrict__ part,
                                               float* __restrict__ abuf, int bBase, size_t pStride)
{
    const float* pz = part + (size_t)blockIdx.y * pStride;
    const int b = bBase + blockIdx.y;
    const int t = threadIdx.x;
    const int hq = blockIdx.x;
    const int h = hq / NQ, q = hq % NQ;
    float mmax = -1e30f;
    for (int c = 0; c < NCHUNK; c++)
        mmax = fmaxf(mmax, pz[((size_t)(h * NCHUNK + c) * 128 + q) * 34]);
    float L = 0.f, a = 0.f;
    for (int c = 0; c < NCHUNK; c++) {
        const float* p = &pz[((size_t)(h * NCHUNK + c) * 128 + q) * 34];
        float wv = __expf(p[0] - mmax);
        L += wv * p[1];
        if (t < DH) a += wv * p[2 + t];
    }
    if (t < DH)
        abuf[((size_t)(b * NQ + q)) * D + h * DH + t] = a / L;
}

// ---------------- self-attention (100x100 per (b,h)) ----------------
__global__ __launch_bounds__(128) void k_sattn(const float* __restrict__ sqkv, float* __restrict__ abuf)
{
    const int tid = threadIdx.x;
    const int bh = blockIdx.x;
    const int b = bh >> 3, h = bh & 7;
    __shared__ float Ks[NQ][DH], Vs[NQ][DH];
    for (int idx = tid; idx < NQ * 8; idx += 128) {
        int kk = idx >> 3, f4 = idx & 7;
        const float* base = sqkv + ((size_t)(b * NQ + kk)) * (3 * D) + h * DH;
        *(float4*)&Ks[kk][f4 * 4] = *(const float4*)(base + D + f4 * 4);
        *(float4*)&Vs[kk][f4 * 4] = *(const float4*)(base + 2 * D + f4 * 4);
    }
    float qr[DH];
    const int q = tid;
    if (q < NQ) {
        const float* Qp = sqkv + ((size_t)(b * NQ + q)) * (3 * D) + h * DH;
        #pragma unroll
        for (int d = 0; d < DH; d += 4) {
            float4 v = *(const float4*)(Qp + d);
            qr[d] = v.x * SM_SCALE; qr[d+1] = v.y * SM_SCALE;
            qr[d+2] = v.z * SM_SCALE; qr[d+3] = v.w * SM_SCALE;
        }
    } else {
        #pragma unroll
        for (int d = 0; d < DH; d++) qr[d] = 0.f;
    }
    __syncthreads();
    float m = -1e30f, l = 0.f, acc[DH];
    #pragma unroll
    for (int d = 0; d < DH; d++) acc[d] = 0.f;
    for (int kk = 0; kk < NQ; kk++) {
        float sc = 0.f;
        #pragma unroll
        for (int d = 0; d < DH; d++) sc += qr[d] * Ks[kk][d];
        if (sc > m) {
            float r = __expf(m - sc);
            l *= r;
            #pragma unroll
            for (int d = 0; d < DH; d++) acc[d] *= r;
            m = sc;
        }
        float p = __expf(sc - m);
        l += p;
        #pragma unroll
        for (int d = 0; d < DH; d++) acc[d] += p * Vs[kk][d];
    }
    if (q < NQ) {
        float li = 1.f / l;
        float* o = abuf + ((size_t)(b * NQ + q)) * D + h * DH;
        #pragma unroll
        for (int d = 0; d < DH; d++) o[d] = acc[d] * li;
    }
}

// ---------------- host ----------------
extern "C" void kernel_launch(void* const* d_in, const int* in_sizes, int n_in,
                              void* d_out, int out_size, void* d_ws, size_t ws_size,
                              hipStream_t stream)
{
    const float* x        = (const float*)d_in[0];
    const float* ip_w     = (const float*)d_in[2];
    const float* ip_b     = (const float*)d_in[3];
    const float* ip_g     = (const float*)d_in[4];
    const float* ip_bb    = (const float*)d_in[5];
    const float* xm_w1    = (const float*)d_in[6];
    const float* xm_b1    = (const float*)d_in[7];
    const float* xm_w2    = (const float*)d_in[8];
    const float* xm_b2    = (const float*)d_in[9];
    const float* qe       = (const float*)d_in[10];
    const float* ca_wqkv  = (const float*)d_in[11];
    const float* ca_bqkv  = (const float*)d_in[12];
    const float* ca_wo    = (const float*)d_in[13];
    const float* ca_bo    = (const float*)d_in[14];
    const float* sa_wqkv  = (const float*)d_in[15];
    const float* sa_bqkv  = (const float*)d_in[16];
    const float* sa_wo    = (const float*)d_in[17];
    const float* sa_bo    = (const float*)d_in[18];
    const float* sa_ln_g  = (const float*)d_in[19];
    const float* sa_ln_b  = (const float*)d_in[20];
    const float* ffn_w1   = (const float*)d_in[21];
    const float* ffn_b1   = (const float*)d_in[22];
    const float* ffn_w2   = (const float*)d_in[23];
    const float* ffn_b2   = (const float*)d_in[24];
    const float* ffn_ln_g = (const float*)d_in[25];
    const float* ffn_ln_b = (const float*)d_in[26];
    const float* out_ln_g = (const float*)d_in[27];
    const float* out_ln_b = (const float*)d_in[28];
    const float* cls_w1   = (const float*)d_in[29];
    const float* cls_b1   = (const float*)d_in[30];
    const float* cls_w2   = (const float*)d_in[31];
    const float* cls_b2   = (const float*)d_in[32];
    float* out = (float*)d_out;

    // ---- workspace tiering (round-5 counters prove ws_size >= 92 MB) ----
    bool batched = false;
    int instRows;
    if      (ws_size >= 210000000ull) { batched = true; instRows = BNi; }
    else if (ws_size >= 112000000ull) { instRows = BNi; }
    else if (ws_size >=  73000000ull) { instRows = Ni;  }
    else return;
    const bool instFull = (instRows == BNi);
    const int nzb = batched ? Bz : 1;

    char* wp = (char*)d_ws;
    auto alloc = [&](size_t bytes) -> char* {
        char* r = wp; wp += (bytes + 255) & ~(size_t)255; return r;
    };
    u16*   instb = (u16*)  alloc((size_t)instRows * D * 2);
    u16*   kvb   = (u16*)  alloc((size_t)(batched ? BNi : Ni) * 2 * D * 2);
    float* part  = (float*)alloc((size_t)nzb * PARTB * 4);
    float* qbuf  = (float*)alloc(409600);
    float* abuf  = (float*)alloc(409600);
    float* sqkv  = (float*)alloc(1228800);
    float* f1b   = (float*)alloc(1638400);
    float* qA    = (float*)alloc(409600);
    float* qB    = (float*)alloc(409600);
    u16*   ipw16 = (u16*)  alloc(256 * 32 * 2);
    u16*   xw116 = (u16*)  alloc(256 * 32 * 2);
    u16*   xw216 = (u16*)  alloc((size_t)D * D * 2);
    u16*   caq16 = (u16*)  alloc((size_t)Ll * 3 * D * D * 2);
    u16*   saq16 = (u16*)  alloc((size_t)Ll * 3 * D * D * 2);
    u16*   cao16 = (u16*)  alloc((size_t)Ll * D * D * 2);
    u16*   sao16 = (u16*)  alloc((size_t)Ll * D * D * 2);
    u16*   fw116 = (u16*)  alloc((size_t)Ll * HIDd * D * 2);
    u16*   fw216 = (u16*)  alloc((size_t)Ll * D * HIDd * 2);
    u16*   qnb   = (u16*)  alloc((size_t)Bz * NQ * D * 2);

    // weight conversions (once per call)
    k_cvt<<<16,   256, 0, stream>>>(ip_w,  ipw16, 256 * 32);
    k_cvt<<<16,   256, 0, stream>>>(xm_w1, xw116, 256 * 32);
    k_cvt<<<64,   256, 0, stream>>>(xm_w2, xw216, D * D);
    k_cvt<<<1024, 256, 0, stream>>>(ca_wqkv, caq16, Ll * 3 * D * D);
    k_cvt<<<1024, 256, 0, stream>>>(sa_wqkv, saq16, Ll * 3 * D * D);
    k_cvt<<<512,  256, 0, stream>>>(ca_wo, cao16, Ll * D * D);
    k_cvt<<<512,  256, 0, stream>>>(sa_wo, sao16, Ll * D * D);
    k_cvt<<<1024, 256, 0, stream>>>(ffn_w1, fw116, Ll * HIDd * D);
    k_cvt<<<1024, 256, 0, stream>>>(ffn_w2, fw216, Ll * D * HIDd);

    if (instFull)
        k_inproj<true><<<(BNi + 127) / 128, 512, 0, stream>>>(
            x, 0, BNi, ipw16, ip_b, ip_g, ip_bb, instb);
    k_bcast<<<Bz * NQ, 256, 0, stream>>>(qe, qA);

    float* qcur = qA;
    float* qtmp = qB;
    for (int i = 0; i < Ll; i++) {
        const u16*   wq16 = caq16 + (size_t)i * 3 * D * D;                 // Q rows
        const u16*   wkv16 = wq16 + (size_t)D * D;                          // K,V rows
        const float* bqkv = ca_bqkv + (size_t)i * 3 * D;
        // Q projection (bf16 MFMA, fp32 out)
        mm_small<false><<<dim3(4, 7), 256, 0, stream>>>(
            qcur, wq16, bqkv, nullptr, qbuf, Bz * NQ, D, D);
        if (batched) {
            mm128<true><<<dim3(4, 196, 4), 256, 0, stream>>>(
                instb, wkv16, bqkv + D, kvb, Ni, 2 * D, D,
                (long long)Ni * D, 0, (long long)Ni * 2 * D);
            k_flash<<<dim3(NCHUNK, Hh, 4), 512, 0, stream>>>(
                qbuf, kvb, part, 0, (size_t)Ni * 2 * D, PARTB);
            k_fmerge<<<dim3(Hh * NQ, 4), 64, 0, stream>>>(part, abuf, 0, PARTB);
        } else {
            for (int b = 0; b < Bz; b++) {
                if (!instFull)
                    k_inproj<true><<<(Ni + 127) / 128, 512, 0, stream>>>(
                        x, b * Ni, Ni, ipw16, ip_b, ip_g, ip_bb, instb);
                const u16* ip = instFull ? instb + (size_t)b * Ni * D : instb;
                mm128<true><<<dim3(4, 196, 1), 256, 0, stream>>>(
                    ip, wkv16, bqkv + D, kvb, Ni, 2 * D, D, 0, 0, 0);
                k_flash<<<dim3(NCHUNK, Hh, 1), 512, 0, stream>>>(
                    qbuf, kvb, part, b, 0, 0);
                k_fmerge<<<dim3(Hh * NQ, 1), 64, 0, stream>>>(part, abuf, b, 0);
            }
        }
        // CA out-proj + pure residual
        mm_small<false><<<dim3(4, 7), 256, 0, stream>>>(
            abuf, cao16 + (size_t)i * D * D, ca_bo + (size_t)i * D, qcur, qtmp,
            Bz * NQ, D, D);
        { float* t2 = qcur; qcur = qtmp; qtmp = t2; }
        // self-attention
        mm_small<false><<<dim3(12, 7), 256, 0, stream>>>(
            qcur, saq16 + (size_t)i * 3 * D * D, sa_bqkv + (size_t)i * 3 * D, nullptr, sqkv,
            Bz * NQ, 3 * D, D);
        k_sattn<<<Bz * Hh, 128, 0, stream>>>(sqkv, abuf);
        mm_small<false><<<dim3(4, 7), 256, 0, stream>>>(
            abuf, sao16 + (size_t)i * D * D, sa_bo + (size_t)i * D, qcur, qtmp,
            Bz * NQ, D, D);
        k_ln<<<Bz * NQ, 256, 0, stream>>>(qtmp, qtmp, sa_ln_g + i * D, sa_ln_b + i * D);
        { float* t2 = qcur; qcur = qtmp; qtmp = t2; }
        // FFN
        mm_small<true><<<dim3(16, 7), 256, 0, stream>>>(
            qcur, fw116 + (size_t)i * HIDd * D, ffn_b1 + (size_t)i * HIDd, nullptr, f1b,
            Bz * NQ, HIDd, D);
        mm_small<false><<<dim3(4, 7), 256, 0, stream>>>(
            f1b, fw216 + (size_t)i * D * HIDd, ffn_b2 + (size_t)i * D, qcur, qtmp,
            Bz * NQ, D, HIDd);
        k_ln<<<Bz * NQ, 256, 0, stream>>>(qtmp, qtmp, ffn_ln_g + i * D, ffn_ln_b + i * D);
        { float* t2 = qcur; qcur = qtmp; qtmp = t2; }
    }

    // final LN into qbuf
    float* qn = qbuf;
    k_ln<<<Bz * NQ, 256, 0, stream>>>(qcur, qn, out_ln_g, out_ln_b);
    // classification head (fp32 for output accuracy)
    k_gemm<64,64,4,4><<<dim3(4, 7), 256, 0, stream>>>(
        qn, cls_w1, cls_b1, nullptr, abuf, Bz * NQ, D, D, 1);
    k_gemm<64,64,4,4><<<dim3(1, 7), 256, 0, stream>>>(
        abuf, cls_w2, cls_b2, nullptr, out, Bz * NQ, NC1, D, 0);

    // mask path (instb/kvb regions dead now)
    k_cvt<<<128, 256, 0, stream>>>(qn, qnb, Bz * NQ * D);
    if (instFull) {
        // full h1 into instb region (51.2 MB fits tiers A/A+)
        k_inproj<false><<<(BNi + 127) / 128, 512, 0, stream>>>(
            x, 0, BNi, xw116, xm_b1, nullptr, nullptr, instb);
        if (batched) {
            mm128<true><<<dim3(2, 196, 4), 256, 0, stream>>>(
                instb, xw216, xm_b2, kvb, Ni, D, D,
                (long long)Ni * D, 0, (long long)Ni * D);
            mm128<false><<<dim3(196, 1, 4), 256, 0, stream>>>(
                qnb, kvb, nullptr, out + Bz * NQ * NC1, NQ, Ni, D,
                (long long)NQ * D, (long long)Ni * D, (long long)NQ * Ni);
        } else {
            for (int b = 0; b < Bz; b++) {
                mm128<true><<<dim3(2, 196, 1), 256, 0, stream>>>(
                    instb + (size_t)b * Ni * D, xw216, xm_b2, kvb, Ni, D, D, 0, 0, 0);
                mm128<false><<<dim3(196, 1, 1), 256, 0, stream>>>(
                    qnb + (size_t)b * NQ * D, kvb, nullptr,
                    out + Bz * NQ * NC1 + (size_t)b * NQ * Ni, NQ, Ni, D, 0, 0, 0);
            }
        }
    } else {
        for (int b = 0; b < Bz; b++) {
            k_inproj<false><<<(Ni + 127) / 128, 512, 0, stream>>>(
                x, b * Ni, Ni, xw116, xm_b1, nullptr, nullptr, instb);
            mm128<true><<<dim3(2, 196, 1), 256, 0, stream>>>(
                instb, xw216, xm_b2, kvb, Ni, D, D, 0, 0, 0);
            mm128<false><<<dim3(196, 1, 1), 256, 0, stream>>>(
                qnb + (size_t)b * NQ * D, kvb, nullptr,
                out + Bz * NQ * NC1 + (size_t)b * NQ * Ni, NQ, Ni, D, 0, 0, 0);
        }
    }
}